// Round 4
// baseline (314.983 us; speedup 1.0000x reference)
//
#include <hip/hip_runtime.h>
#include <hip/hip_bf16.h>
#include <math.h>

#define BB   2
#define TT   2048
#define DD   768
#define HH   12
#define HD   64
#define MM   (BB*TT)
#define BTD  ((long)BB*TT*DD)

typedef __bf16 bf16x8 __attribute__((ext_vector_type(8)));
typedef __bf16 bf16x4 __attribute__((ext_vector_type(4)));
typedef float  f32x4  __attribute__((ext_vector_type(4)));

// ---------------------------------------------------------------------------
// fp32 -> bf16 convert
// ---------------------------------------------------------------------------
__global__ __launch_bounds__(256) void cvt_bf16(
    const float* __restrict__ in, __bf16* __restrict__ out, int n4)
{
    const int i = blockIdx.x * 256 + threadIdx.x;
    if (i < n4) {
        const float4 v = ((const float4*)in)[i];
        bf16x4 o;
        o.x = (__bf16)v.x; o.y = (__bf16)v.y;
        o.z = (__bf16)v.z; o.w = (__bf16)v.w;
        ((bf16x4*)out)[i] = o;
    }
}

// ---------------------------------------------------------------------------
// bf16 MFMA GEMM: Y = A @ B^T + bias. mode 1 also writes bf16 q/k (Yb).
// ---------------------------------------------------------------------------
__global__ __launch_bounds__(256) void mfma_gemm(
    const __bf16* __restrict__ A, const __bf16* __restrict__ Bw,
    const float* __restrict__ b0, const float* __restrict__ b1,
    const float* __restrict__ b2, float* __restrict__ Y,
    __bf16* __restrict__ Yb, int N, int mode)
{
    constexpr int K = DD;
    __shared__ __bf16 As[128 * 32];
    __shared__ __bf16 Bs[128 * 32];

    const int tid  = threadIdx.x;
    const int wid  = tid >> 6, lane = tid & 63;
    const int m0   = blockIdx.y * 128, n0 = blockIdx.x * 128;
    const int wr   = wid >> 1, wc = wid & 1;

    f32x4 acc[4][4] = {};

    const char* Ag = (const char*)(A + (long)m0 * K);
    const char* Bg = (const char*)(Bw + (long)n0 * K);

    for (int k0 = 0; k0 < K; k0 += 32) {
        #pragma unroll
        for (int c = 0; c < 2; c++) {
            const int o   = wid * 2048 + c * 1024 + lane * 16;
            const int row = o >> 6, kb = o & 63;
            const long goff = (long)row * (K * 2) + k0 * 2 + kb;
            __builtin_amdgcn_global_load_lds(
                (const __attribute__((address_space(1))) void*)(Ag + goff),
                (__attribute__((address_space(3))) void*)((char*)As + wid * 2048 + c * 1024),
                16, 0, 0);
            __builtin_amdgcn_global_load_lds(
                (const __attribute__((address_space(1))) void*)(Bg + goff),
                (__attribute__((address_space(3))) void*)((char*)Bs + wid * 2048 + c * 1024),
                16, 0, 0);
        }
        __syncthreads();

        bf16x8 af[4], bfr[4];
        #pragma unroll
        for (int m = 0; m < 4; m++)
            af[m] = *(const bf16x8*)(As + ((wr * 64 + m * 16 + (lane & 15)) * 32 + (lane >> 4) * 8));
        #pragma unroll
        for (int n = 0; n < 4; n++)
            bfr[n] = *(const bf16x8*)(Bs + ((wc * 64 + n * 16 + (lane & 15)) * 32 + (lane >> 4) * 8));
        #pragma unroll
        for (int m = 0; m < 4; m++)
            #pragma unroll
            for (int n = 0; n < 4; n++)
                acc[m][n] = __builtin_amdgcn_mfma_f32_16x16x32_bf16(
                    af[m], bfr[n], acc[m][n], 0, 0, 0);
        __syncthreads();
    }

    const int fq = lane >> 4, fr = lane & 15;
    #pragma unroll
    for (int m = 0; m < 4; m++) {
        const int grow = m0 + wr * 64 + m * 16 + fq * 4;
        #pragma unroll
        for (int n = 0; n < 4; n++) {
            const int col = n0 + wc * 64 + n * 16 + fr;
            if (mode == 0) {
                const float bias = b0[col];
                #pragma unroll
                for (int j = 0; j < 4; j++)
                    Y[(long)(grow + j) * N + col] = acc[m][n][j] + bias;
            } else {
                const int which = col / DD;
                const int nn = col - which * DD;
                const float* bp = which == 0 ? b0 : (which == 1 ? b1 : b2);
                const float bias = bp[nn];
                const int h_ = nn >> 6, d_ = nn & 63;
                float* base = Y + (long)which * BTD;
                __bf16* baseb = Yb + (long)which * BTD;
                #pragma unroll
                for (int j = 0; j < 4; j++) {
                    const int row = grow + j;
                    const int b_ = row >> 11, t_ = row & (TT - 1);
                    const long idx = (((long)b_ * HH + h_) * TT + t_) * HD + d_;
                    const float val = acc[m][n][j] + bias;
                    base[idx] = val;
                    if (which < 2) baseb[idx] = (__bf16)val;   // bf16 q, k
                }
            }
        }
    }
}

// ---------------------------------------------------------------------------
// v (fp32, b,h,t,d) -> vT (bf16, b,h,d,t) tiled transpose
// ---------------------------------------------------------------------------
__global__ __launch_bounds__(256) void vt_transpose(
    const float* __restrict__ V, __bf16* __restrict__ vT)
{
    const int t0 = blockIdx.x * 64, h = blockIdx.y, b = blockIdx.z;
    const int tid = threadIdx.x;
    __shared__ float tl[64][65];
    const float* vb = V + (((long)b * HH + h) * TT + t0) * HD;
    for (int i = tid; i < 64 * 64; i += 256)
        tl[i >> 6][i & 63] = vb[i];
    __syncthreads();
    __bf16* ob = vT + ((long)b * HH + h) * HD * TT + t0;
    for (int i = tid; i < 64 * 64; i += 256) {
        const int d = i >> 6, t = i & 63;
        ob[(long)d * TT + t] = (__bf16)tl[t][d];
    }
}

// ---------------------------------------------------------------------------
// Extract the 16 random key columns per row (rows 32..2047).
// ---------------------------------------------------------------------------
__global__ __launch_bounds__(64) void extract_rand(
    const void* __restrict__ maskp, int* __restrict__ rand_idx)
{
    const int row = blockIdx.x + 32;
    const int lane = threadIdx.x;
    const unsigned char* m8 = (const unsigned char*)maskp;
    const int* m32 = (const int*)maskp;
    const bool u8 = (m8[1] != 0);

    int loc[16];
    int cnt = 0;
    const int c0 = lane * 32;
    for (int t = 0; t < 32; t++) {
        int c = c0 + t;
        int d = c - row;
        if (c >= 32 && (d > 64 || d < -64)) {
            int mv = u8 ? (int)m8[(long)row * TT + c] : m32[(long)row * TT + c];
            if (mv && cnt < 16) loc[cnt++] = c;
        }
    }
    int incl = cnt;
    for (int d = 1; d < 64; d <<= 1) {
        int n = __shfl_up(incl, d, 64);
        if (lane >= d) incl += n;
    }
    const int excl = incl - cnt;
    for (int i = 0; i < cnt; i++) {
        int p = excl + i;
        if (p < 16) rand_idx[(long)row * 16 + p] = loc[i];
    }
    const int total = __shfl(incl, 63, 64);
    if (lane == 0)
        for (int p = total; p < 16; p++) rand_idx[(long)row * 16 + p] = -1;
}

// ---------------------------------------------------------------------------
// Dense global rows 0..31 (fp32 scalar flash partials) — unchanged.
// ---------------------------------------------------------------------------
__global__ __launch_bounds__(256) void bb_dense_rows(
    const float* __restrict__ Q, const float* __restrict__ Kg,
    const float* __restrict__ V, float* __restrict__ part)
{
    const int ch = blockIdx.x, h = blockIdx.y, b = blockIdx.z;
    const int tid = threadIdx.x;
    __shared__ float qs[32][65];
    __shared__ float ks[64][65];
    __shared__ float vs[64][65];
    __shared__ float ps[32][65];

    const float* qb = Q + ((long)b * HH + h) * TT * HD;
    for (int i = tid; i < 32 * 64; i += 256) qs[i >> 6][i & 63] = qb[i];

    const int r = tid >> 3, g = tid & 7, dsl = g * 8;
    float acc[8] = {};
    float mrow = -INFINITY, lrow = 0.f;
    const float* kb = Kg + ((long)b * HH + h) * TT * HD;
    const float* vb = V + ((long)b * HH + h) * TT * HD;

    for (int t = 0; t < 4; t++) {
        const int k0 = ch * 256 + t * 64;
        __syncthreads();
        for (int i = tid; i < 64 * 64; i += 256) {
            ks[i >> 6][i & 63] = kb[(long)k0 * 64 + i];
            vs[i >> 6][i & 63] = vb[(long)k0 * 64 + i];
        }
        __syncthreads();
        float s[8] = {};
        for (int d = 0; d < 64; d++) {
            float qv = qs[r][d];
            #pragma unroll
            for (int j = 0; j < 8; j++) s[j] += qv * ks[g * 8 + j][d];
        }
        float tm = -INFINITY;
        #pragma unroll
        for (int j = 0; j < 8; j++) { s[j] *= 0.125f; tm = fmaxf(tm, s[j]); }
        #pragma unroll
        for (int o = 1; o < 8; o <<= 1) tm = fmaxf(tm, __shfl_xor(tm, o, 64));
        const float newm = fmaxf(mrow, tm);
        const float corr = (mrow == newm) ? 1.f : __expf(mrow - newm);
        float psum = 0.f;
        #pragma unroll
        for (int j = 0; j < 8; j++) {
            float p = __expf(s[j] - newm);
            ps[r][g * 8 + j] = p; psum += p;
        }
        #pragma unroll
        for (int o = 1; o < 8; o <<= 1) psum += __shfl_xor(psum, o, 64);
        lrow = lrow * corr + psum; mrow = newm;
        #pragma unroll
        for (int j = 0; j < 8; j++) acc[j] *= corr;
        #pragma unroll 4
        for (int kk = 0; kk < 64; kk++) {
            float p = ps[r][kk];
            #pragma unroll
            for (int j = 0; j < 8; j++) acc[j] += p * vs[kk][dsl + j];
        }
    }
    float* pb = part + ((((long)b * HH + h) * 8 + ch) * 32 + r) * 66;
    if (g == 0) { pb[0] = mrow; pb[1] = lrow; }
    #pragma unroll
    for (int j = 0; j < 8; j++) pb[2 + dsl + j] = acc[j];
}

__global__ __launch_bounds__(256) void bb_dense_combine(
    const float* __restrict__ part, __bf16* __restrict__ Ao)
{
    const int h = blockIdx.x, b = blockIdx.y;
    const int tid = threadIdx.x;
    const int r = tid >> 3, dsl = (tid & 7) * 8;
    const float* pb = part + (((long)b * HH + h) * 8 * 32 + r) * 66;
    float M = -INFINITY;
    #pragma unroll
    for (int c = 0; c < 8; c++) M = fmaxf(M, pb[(long)c * 32 * 66]);
    float L = 0.f, o[8] = {};
    #pragma unroll
    for (int c = 0; c < 8; c++) {
        const float* pc = pb + (long)c * 32 * 66;
        const float w = __expf(pc[0] - M);
        L += w * pc[1];
        #pragma unroll
        for (int j = 0; j < 8; j++) o[j] += w * pc[2 + dsl + j];
    }
    const float inv = 1.f / L;
    const long ob = ((long)b * TT + r) * DD + h * HD + dsl;
    #pragma unroll
    for (int j = 0; j < 8; j++) Ao[ob + j] = (__bf16)(o[j] * inv);
}

// ---------------------------------------------------------------------------
// MFMA BigBird sparse rows 32..2047.
// Per block: 32 q-rows, keys = G(32) + band(160 padded, masked) + 16 rand/row.
// Phases: stage Q,K -> S=QK^T (MFMA) + rand scores (scalar) -> softmax
// (P aliases S) -> stage V^T over K -> O=PV (MFMA) -> epilogue (+rand PV).
// ---------------------------------------------------------------------------
#define KSB 192          // MFMA key count (G 32 + band 160)
#define KTOT 208         // + 16 randoms
#define QSTR 72          // Qs/Ks stride (bf16)
#define VSTR 216         // VT stride (bf16)
#define SSTR 212         // S stride (f32);  P stride = 424 bf16 (same bytes)

__global__ __launch_bounds__(256) void bb_sparse_mfma(
    const __bf16* __restrict__ Qb, const __bf16* __restrict__ Kb,
    const float* __restrict__ Vf, const __bf16* __restrict__ vT,
    const int* __restrict__ rand_idx, __bf16* __restrict__ Ao)
{
    const int q0 = (blockIdx.x + 1) * 32;
    const int h = blockIdx.y, b = blockIdx.z;
    const int tid = threadIdx.x;
    const int w = tid >> 6, lane = tid & 63;
    const int fq = lane >> 4, fr = lane & 15;
    const int rh = w & 1, cg = w >> 1, dg = w >> 1;

    const int lo = max(32, q0 - 64);
    const int hi = min(TT - 1, q0 + 95);

    __shared__ __bf16 Qs[32 * QSTR];
    __shared__ __bf16 KVT[KSB * QSTR];     // K tile, later V^T tile
    __shared__ float  Sb[32 * SSTR];       // S f32, later P bf16 (aliased)
    __shared__ float  lrow_s[32];

    const __bf16* qbase = Qb + (((long)b * HH + h) * TT + q0) * HD;
    const __bf16* kbase = Kb + ((long)b * HH + h) * TT * HD;
    const float*  vbase = Vf + ((long)b * HH + h) * TT * HD;
    const __bf16* vTbase = vT + ((long)b * HH + h) * HD * TT;

    // ---- stage Q (32x64) ----
    {
        const int r = tid >> 3, d0 = (tid & 7) * 8;
        *(bf16x8*)(Qs + r * QSTR + d0) = *(const bf16x8*)(qbase + r * 64 + d0);
    }
    // ---- stage K (192x64): rows 0..31 = G keys, 32.. = band lo.. ----
    #pragma unroll
    for (int c = 0; c < 6; c++) {
        const int key = c * 32 + (tid >> 3);
        const int d0 = (tid & 7) * 8;
        int t = key < 32 ? key : lo + (key - 32);
        t = min(t, TT - 1);
        *(bf16x8*)(KVT + key * QSTR + d0) = *(const bf16x8*)(kbase + (long)t * 64 + d0);
    }
    __syncthreads();

    // ---- S = Q K^T via MFMA: wave (rh, cg) does 6 col-tiles ----
    {
        const int rowA = rh * 16 + fr;
        bf16x8 aq[2];
        #pragma unroll
        for (int kk = 0; kk < 2; kk++)
            aq[kk] = *(const bf16x8*)(Qs + rowA * QSTR + kk * 32 + fq * 8);
        #pragma unroll
        for (int ct6 = 0; ct6 < 6; ct6++) {
            const int ct = cg * 6 + ct6;
            const int key = ct * 16 + fr;
            f32x4 sc = {};
            #pragma unroll
            for (int kk = 0; kk < 2; kk++) {
                const bf16x8 bk = *(const bf16x8*)(KVT + key * QSTR + kk * 32 + fq * 8);
                sc = __builtin_amdgcn_mfma_f32_16x16x32_bf16(aq[kk], bk, sc, 0, 0, 0);
            }
            const int colg = ct * 16 + fr;
            const int keyg = colg < 32 ? colg : lo + (colg - 32);
            #pragma unroll
            for (int j = 0; j < 4; j++) {
                const int rloc = rh * 16 + fq * 4 + j;
                const int grow = q0 + rloc;
                const int dlt = keyg - grow;
                const bool valid = (colg < 32) ||
                                   (keyg <= hi && dlt <= 64 && dlt >= -64);
                Sb[rloc * SSTR + colg] = valid ? sc[j] * 0.125f : -INFINITY;
            }
        }
    }

    // ---- rand scores (scalar): thread (r, g) does 2 cols ----
    {
        const int r = tid >> 3, g = tid & 7;
        const int grow = q0 + r;
        const int* rr = rand_idx + (long)grow * 16;
        float qv[64];
        #pragma unroll
        for (int w8 = 0; w8 < 8; w8++) {
            const bf16x8 q8 = *(const bf16x8*)(Qs + r * QSTR + w8 * 8);
            #pragma unroll
            for (int e = 0; e < 8; e++) qv[w8 * 8 + e] = (float)q8[e];
        }
        #pragma unroll
        for (int t = 0; t < 2; t++) {
            const int c = rr[g * 2 + t];
            const __bf16* kr = kbase + (long)max(c, 0) * 64;
            float s = 0.f;
            #pragma unroll
            for (int w8 = 0; w8 < 8; w8++) {
                const bf16x8 k8 = *(const bf16x8*)(kr + w8 * 8);
                #pragma unroll
                for (int e = 0; e < 8; e++) s += qv[w8 * 8 + e] * (float)k8[e];
            }
            Sb[r * SSTR + KSB + g * 2 + t] = (c >= 0) ? s * 0.125f : -INFINITY;
        }
    }
    __syncthreads();

    // ---- softmax: 8 lanes/row (same wave), 26 cols each; P aliases S ----
    {
        const int r = tid >> 3, seg = tid & 7;
        float sv[26];
        float m = -INFINITY;
        #pragma unroll
        for (int i = 0; i < 26; i++) {
            sv[i] = Sb[r * SSTR + seg * 26 + i];
            m = fmaxf(m, sv[i]);
        }
        #pragma unroll
        for (int o = 1; o < 8; o <<= 1) m = fmaxf(m, __shfl_xor(m, o, 64));
        float l = 0.f;
        #pragma unroll
        for (int i = 0; i < 26; i++) {
            sv[i] = (sv[i] == -INFINITY) ? 0.f : __expf(sv[i] - m);
            l += sv[i];
        }
        #pragma unroll
        for (int o = 1; o < 8; o <<= 1) l += __shfl_xor(l, o, 64);
        __bf16* Pl = (__bf16*)Sb;
        #pragma unroll
        for (int i = 0; i < 26; i++)
            Pl[r * (SSTR * 2) + seg * 26 + i] = (__bf16)sv[i];
        if (seg == 0) lrow_s[r] = l;
    }

    // ---- stage V^T (64 d x 192 keys) into KVT ----
    #pragma unroll
    for (int c = 0; c < 6; c++) {
        const int idx = c * 256 + tid;
        const int d = idx / 24, cj = idx % 24;
        const int j0 = cj * 8;
        int t0 = j0 < 32 ? j0 : lo + (j0 - 32);
        t0 = min(t0, TT - 8);
        *(bf16x8*)(KVT + d * VSTR + j0) = *(const bf16x8*)(vTbase + (long)d * TT + t0);
    }
    __syncthreads();

    // ---- O = P V via MFMA: wave (rh, dg) does 2 d-tiles over 6 k-slices ----
    f32x4 ov[2] = {};
    {
        const __bf16* Pl = (const __bf16*)Sb;
        const int rowP = rh * 16 + fr;
        #pragma unroll
        for (int kk = 0; kk < 6; kk++) {
            const bf16x8 ap = *(const bf16x8*)(Pl + rowP * (SSTR * 2) + kk * 32 + fq * 8);
            #pragma unroll
            for (int ti = 0; ti < 2; ti++) {
                const int d = (dg * 2 + ti) * 16 + fr;
                const bf16x8 bv = *(const bf16x8*)(KVT + d * VSTR + kk * 32 + fq * 8);
                ov[ti] = __builtin_amdgcn_mfma_f32_16x16x32_bf16(ap, bv, ov[ti], 0, 0, 0);
            }
        }
    }

    // ---- epilogue: + rand PV, normalize, store bf16 ----
    {
        const __bf16* Pl = (const __bf16*)Sb;
        #pragma unroll
        for (int ti = 0; ti < 2; ti++) {
            const int dcol = (dg * 2 + ti) * 16 + fr;
            #pragma unroll
            for (int j = 0; j < 4; j++) {
                const int rloc = rh * 16 + fq * 4 + j;
                const int grow = q0 + rloc;
                float o = ov[ti][j];
                const int* rr = rand_idx + (long)grow * 16;
                #pragma unroll 4
                for (int t = 0; t < 16; t++) {
                    const float p = (float)Pl[rloc * (SSTR * 2) + KSB + t];
                    const int c = rr[t];
                    if (c >= 0) o += p * vbase[(long)c * 64 + dcol];
                }
                o *= 1.f / lrow_s[rloc];
                Ao[((long)b * TT + grow) * DD + h * HD + dcol] = (__bf16)o;
            }
        }
    }
}

// ---------------------------------------------------------------------------
extern "C" void kernel_launch(void* const* d_in, const int* in_sizes, int n_in,
                              void* d_out, int out_size, void* d_ws, size_t ws_size,
                              hipStream_t stream)
{
    const float* x  = (const float*)d_in[0];
    const float* Wq = (const float*)d_in[1];
    const float* bq = (const float*)d_in[2];
    const float* Wk = (const float*)d_in[3];
    const float* bk = (const float*)d_in[4];
    const float* Wv = (const float*)d_in[5];
    const float* bv = (const float*)d_in[6];
    const float* Wo = (const float*)d_in[7];
    const float* bo = (const float*)d_in[8];
    const void*  mask = d_in[9];

    float* q = (float*)d_ws;
    float* k = q + BTD;
    float* v = k + BTD;
    __bf16* xb   = (__bf16*)(v + BTD);
    __bf16* aob  = xb + BTD;
    __bf16* Wcat = aob + BTD;
    __bf16* Wob  = Wcat + (long)3 * DD * DD;
    __bf16* qkb  = Wob + (long)DD * DD;        // bf16 q | k  (2*BTD)
    __bf16* vTb  = qkb + 2 * BTD;              // bf16 v^T    (BTD)
    int*    rand_idx = (int*)(vTb + BTD);
    float*  part = (float*)(rand_idx + (long)TT * 16);

    extract_rand<<<TT - 32, 64, 0, stream>>>(mask, rand_idx);

    const int WN4 = DD * DD / 4;
    cvt_bf16<<<(int)(BTD / 4 + 255) / 256, 256, 0, stream>>>(x, xb, (int)(BTD / 4));
    cvt_bf16<<<(WN4 + 255) / 256, 256, 0, stream>>>(Wq, Wcat, WN4);
    cvt_bf16<<<(WN4 + 255) / 256, 256, 0, stream>>>(Wk, Wcat + (long)DD * DD, WN4);
    cvt_bf16<<<(WN4 + 255) / 256, 256, 0, stream>>>(Wv, Wcat + (long)2 * DD * DD, WN4);
    cvt_bf16<<<(WN4 + 255) / 256, 256, 0, stream>>>(Wo, Wob, WN4);

    mfma_gemm<<<dim3(3 * DD / 128, MM / 128), 256, 0, stream>>>(
        xb, Wcat, bq, bk, bv, q, qkb, 3 * DD, 1);

    vt_transpose<<<dim3(TT / 64, HH, BB), 256, 0, stream>>>(v, vTb);

    bb_dense_rows<<<dim3(8, HH, BB), 256, 0, stream>>>(q, k, v, part);
    bb_dense_combine<<<dim3(HH, BB), 256, 0, stream>>>(part, aob);

    bb_sparse_mfma<<<dim3(TT / 32 - 1, HH, BB), 256, 0, stream>>>(
        qkb, qkb + BTD, v, vTb, rand_idx, aob);

    mfma_gemm<<<dim3(DD / 128, MM / 128), 256, 0, stream>>>(
        aob, Wob, bo, bo, bo, (float*)d_out, nullptr, DD, 0);
}

// Round 5
// 180.920 us; speedup vs baseline: 1.7410x; 1.7410x over previous
//
#include <hip/hip_runtime.h>
#include <hip/hip_bf16.h>
#include <math.h>

#define BB   2
#define TT   2048
#define DD   768
#define HH   12
#define HD   64
#define MM   (BB*TT)
#define BTD  ((long)BB*TT*DD)

typedef __bf16 bf16x8 __attribute__((ext_vector_type(8)));
typedef __bf16 bf16x4 __attribute__((ext_vector_type(4)));
typedef float  f32x4  __attribute__((ext_vector_type(4)));

// ---------------------------------------------------------------------------
// fp32 -> bf16 convert
// ---------------------------------------------------------------------------
__global__ __launch_bounds__(256) void cvt_bf16(
    const float* __restrict__ in, __bf16* __restrict__ out, int n4)
{
    const int i = blockIdx.x * 256 + threadIdx.x;
    if (i < n4) {
        const float4 v = ((const float4*)in)[i];
        bf16x4 o;
        o.x = (__bf16)v.x; o.y = (__bf16)v.y;
        o.z = (__bf16)v.z; o.w = (__bf16)v.w;
        ((bf16x4*)out)[i] = o;
    }
}

// ---------------------------------------------------------------------------
// bf16 MFMA GEMM: Y = A @ B^T + bias.
//   mode 0: fp32 Y row-major (N=768)
//   mode 1: N=2304 -> bf16 q|k|v in (B,H,T,HD) layout (Yb base, 3*BTD)
// ---------------------------------------------------------------------------
__global__ __launch_bounds__(256) void mfma_gemm(
    const __bf16* __restrict__ A, const __bf16* __restrict__ Bw,
    const float* __restrict__ b0, const float* __restrict__ b1,
    const float* __restrict__ b2, float* __restrict__ Y,
    __bf16* __restrict__ Yb, int N, int mode)
{
    constexpr int K = DD;
    __shared__ __bf16 As[128 * 32];
    __shared__ __bf16 Bs[128 * 32];

    const int tid  = threadIdx.x;
    const int wid  = tid >> 6, lane = tid & 63;
    const int m0   = blockIdx.y * 128, n0 = blockIdx.x * 128;
    const int wr   = wid >> 1, wc = wid & 1;

    f32x4 acc[4][4] = {};

    const char* Ag = (const char*)(A + (long)m0 * K);
    const char* Bg = (const char*)(Bw + (long)n0 * K);

    for (int k0 = 0; k0 < K; k0 += 32) {
        #pragma unroll
        for (int c = 0; c < 2; c++) {
            const int o   = wid * 2048 + c * 1024 + lane * 16;
            const int row = o >> 6, kb = o & 63;
            const long goff = (long)row * (K * 2) + k0 * 2 + kb;
            __builtin_amdgcn_global_load_lds(
                (const __attribute__((address_space(1))) void*)(Ag + goff),
                (__attribute__((address_space(3))) void*)((char*)As + wid * 2048 + c * 1024),
                16, 0, 0);
            __builtin_amdgcn_global_load_lds(
                (const __attribute__((address_space(1))) void*)(Bg + goff),
                (__attribute__((address_space(3))) void*)((char*)Bs + wid * 2048 + c * 1024),
                16, 0, 0);
        }
        __syncthreads();

        bf16x8 af[4], bfr[4];
        #pragma unroll
        for (int m = 0; m < 4; m++)
            af[m] = *(const bf16x8*)(As + ((wr * 64 + m * 16 + (lane & 15)) * 32 + (lane >> 4) * 8));
        #pragma unroll
        for (int n = 0; n < 4; n++)
            bfr[n] = *(const bf16x8*)(Bs + ((wc * 64 + n * 16 + (lane & 15)) * 32 + (lane >> 4) * 8));
        #pragma unroll
        for (int m = 0; m < 4; m++)
            #pragma unroll
            for (int n = 0; n < 4; n++)
                acc[m][n] = __builtin_amdgcn_mfma_f32_16x16x32_bf16(
                    af[m], bfr[n], acc[m][n], 0, 0, 0);
        __syncthreads();
    }

    const int fq = lane >> 4, fr = lane & 15;
    #pragma unroll
    for (int m = 0; m < 4; m++) {
        const int grow = m0 + wr * 64 + m * 16 + fq * 4;
        #pragma unroll
        for (int n = 0; n < 4; n++) {
            const int col = n0 + wc * 64 + n * 16 + fr;
            if (mode == 0) {
                const float bias = b0[col];
                #pragma unroll
                for (int j = 0; j < 4; j++)
                    Y[(long)(grow + j) * N + col] = acc[m][n][j] + bias;
            } else {
                const int which = col / DD;
                const int nn = col - which * DD;
                const float* bp = which == 0 ? b0 : (which == 1 ? b1 : b2);
                const float bias = bp[nn];
                const int h_ = nn >> 6, d_ = nn & 63;
                __bf16* baseb = Yb + (long)which * BTD;
                #pragma unroll
                for (int j = 0; j < 4; j++) {
                    const int row = grow + j;
                    const int b_ = row >> 11, t_ = row & (TT - 1);
                    baseb[(((long)b_ * HH + h_) * TT + t_) * HD + d_] =
                        (__bf16)(acc[m][n][j] + bias);
                }
            }
        }
    }
}

// ---------------------------------------------------------------------------
// v bf16 (b,h,t,d) -> vT bf16 (b,h,d,t)
// ---------------------------------------------------------------------------
__global__ __launch_bounds__(256) void vt_transpose(
    const __bf16* __restrict__ V, __bf16* __restrict__ vT)
{
    const int t0 = blockIdx.x * 64, h = blockIdx.y, b = blockIdx.z;
    const int tid = threadIdx.x;
    __shared__ float tl[64][65];
    const __bf16* vb = V + (((long)b * HH + h) * TT + t0) * HD;
    for (int i = tid; i < 64 * 64; i += 256)
        tl[i >> 6][i & 63] = (float)vb[i];
    __syncthreads();
    __bf16* ob = vT + ((long)b * HH + h) * HD * TT + t0;
    for (int i = tid; i < 64 * 64; i += 256) {
        const int d = i >> 6, t = i & 63;
        ob[(long)d * TT + t] = (__bf16)tl[t][d];
    }
}

// ---------------------------------------------------------------------------
// Extract the 16 random key columns per row (rows 32..2047).
// ---------------------------------------------------------------------------
__global__ __launch_bounds__(64) void extract_rand(
    const void* __restrict__ maskp, int* __restrict__ rand_idx)
{
    const int row = blockIdx.x + 32;
    const int lane = threadIdx.x;
    const unsigned char* m8 = (const unsigned char*)maskp;
    const int* m32 = (const int*)maskp;
    const bool u8 = (m8[1] != 0);

    int loc[16];
    int cnt = 0;
    const int c0 = lane * 32;
    for (int t = 0; t < 32; t++) {
        int c = c0 + t;
        int d = c - row;
        if (c >= 32 && (d > 64 || d < -64)) {
            int mv = u8 ? (int)m8[(long)row * TT + c] : m32[(long)row * TT + c];
            if (mv && cnt < 16) loc[cnt++] = c;
        }
    }
    int incl = cnt;
    for (int d = 1; d < 64; d <<= 1) {
        int n = __shfl_up(incl, d, 64);
        if (lane >= d) incl += n;
    }
    const int excl = incl - cnt;
    for (int i = 0; i < cnt; i++) {
        int p = excl + i;
        if (p < 16) rand_idx[(long)row * 16 + p] = loc[i];
    }
    const int total = __shfl(incl, 63, 64);
    if (lane == 0)
        for (int p = total; p < 16; p++) rand_idx[(long)row * 16 + p] = -1;
}

// ---------------------------------------------------------------------------
// Dense global rows 0..31 (bf16 inputs, fp32 math) flash partials.
// ---------------------------------------------------------------------------
__global__ __launch_bounds__(256) void bb_dense_rows(
    const __bf16* __restrict__ Q, const __bf16* __restrict__ Kg,
    const __bf16* __restrict__ V, float* __restrict__ part)
{
    const int ch = blockIdx.x, h = blockIdx.y, b = blockIdx.z;
    const int tid = threadIdx.x;
    __shared__ float qs[32][65];
    __shared__ float ks[64][65];
    __shared__ float vs[64][65];
    __shared__ float ps[32][65];

    const __bf16* qb = Q + ((long)b * HH + h) * TT * HD;
    for (int i = tid; i < 32 * 64; i += 256) qs[i >> 6][i & 63] = (float)qb[i];

    const int r = tid >> 3, g = tid & 7, dsl = g * 8;
    float acc[8] = {};
    float mrow = -INFINITY, lrow = 0.f;
    const __bf16* kb = Kg + ((long)b * HH + h) * TT * HD;
    const __bf16* vb = V + ((long)b * HH + h) * TT * HD;

    for (int t = 0; t < 4; t++) {
        const int k0 = ch * 256 + t * 64;
        __syncthreads();
        for (int i = tid; i < 64 * 64; i += 256) {
            ks[i >> 6][i & 63] = (float)kb[(long)k0 * 64 + i];
            vs[i >> 6][i & 63] = (float)vb[(long)k0 * 64 + i];
        }
        __syncthreads();
        float s[8] = {};
        for (int d = 0; d < 64; d++) {
            float qv = qs[r][d];
            #pragma unroll
            for (int j = 0; j < 8; j++) s[j] += qv * ks[g * 8 + j][d];
        }
        float tm = -INFINITY;
        #pragma unroll
        for (int j = 0; j < 8; j++) { s[j] *= 0.125f; tm = fmaxf(tm, s[j]); }
        #pragma unroll
        for (int o = 1; o < 8; o <<= 1) tm = fmaxf(tm, __shfl_xor(tm, o, 64));
        const float newm = fmaxf(mrow, tm);
        const float corr = (mrow == newm) ? 1.f : __expf(mrow - newm);
        float psum = 0.f;
        #pragma unroll
        for (int j = 0; j < 8; j++) {
            float p = __expf(s[j] - newm);
            ps[r][g * 8 + j] = p; psum += p;
        }
        #pragma unroll
        for (int o = 1; o < 8; o <<= 1) psum += __shfl_xor(psum, o, 64);
        lrow = lrow * corr + psum; mrow = newm;
        #pragma unroll
        for (int j = 0; j < 8; j++) acc[j] *= corr;
        #pragma unroll 4
        for (int kk = 0; kk < 64; kk++) {
            float p = ps[r][kk];
            #pragma unroll
            for (int j = 0; j < 8; j++) acc[j] += p * vs[kk][dsl + j];
        }
    }
    float* pb = part + ((((long)b * HH + h) * 8 + ch) * 32 + r) * 66;
    if (g == 0) { pb[0] = mrow; pb[1] = lrow; }
    #pragma unroll
    for (int j = 0; j < 8; j++) pb[2 + dsl + j] = acc[j];
}

__global__ __launch_bounds__(256) void bb_dense_combine(
    const float* __restrict__ part, __bf16* __restrict__ Ao)
{
    const int h = blockIdx.x, b = blockIdx.y;
    const int tid = threadIdx.x;
    const int r = tid >> 3, dsl = (tid & 7) * 8;
    const float* pb = part + (((long)b * HH + h) * 8 * 32 + r) * 66;
    float M = -INFINITY;
    #pragma unroll
    for (int c = 0; c < 8; c++) M = fmaxf(M, pb[(long)c * 32 * 66]);
    float L = 0.f, o[8] = {};
    #pragma unroll
    for (int c = 0; c < 8; c++) {
        const float* pc = pb + (long)c * 32 * 66;
        const float w = __expf(pc[0] - M);
        L += w * pc[1];
        #pragma unroll
        for (int j = 0; j < 8; j++) o[j] += w * pc[2 + dsl + j];
    }
    const float inv = 1.f / L;
    const long ob = ((long)b * TT + r) * DD + h * HD + dsl;
    #pragma unroll
    for (int j = 0; j < 8; j++) Ao[ob + j] = (__bf16)(o[j] * inv);
}

// ---------------------------------------------------------------------------
// Sparse rows 32..2047, v2: zero-staging MFMA flash tile.
// All Q/K/V^T MFMA fragments read directly from global (L2-resident slabs).
// S lives in registers; softmax in-register with tiny LDS m/l combine.
// Only P (32x192 bf16, XOR-swizzled) goes through LDS. Randoms: coalesced
// bf16 gathers, p kept in registers, scalar PV.
// Waves: w&1 = q-half (16 rows), w>>1 = key-half (96 keys) / d-half (32 d).
// ---------------------------------------------------------------------------
#define PROWB 384   // P row stride in bytes (192 bf16)
#define SW(r) (((r) & 7) << 4)

__global__ __launch_bounds__(256) void bb_sparse2(
    const __bf16* __restrict__ Qb, const __bf16* __restrict__ Kb,
    const __bf16* __restrict__ Vb, const __bf16* __restrict__ vT,
    const int* __restrict__ rand_idx, __bf16* __restrict__ Ao)
{
    const int q0 = (blockIdx.x + 1) * 32;
    const int h = blockIdx.y, b = blockIdx.z;
    const int tid = threadIdx.x;
    const int w = tid >> 6, lane = tid & 63;
    const int fq = lane >> 4, fr = lane & 15;
    const int qh = w & 1, kr = w >> 1;

    const int lo = max(32, q0 - 64);
    const int hi = min(TT - 1, q0 + 95);

    __shared__ __attribute__((aligned(16))) char Pmem[32 * PROWB]; // P; later Obuf f32[32][68]
    __shared__ float mbuf[2][32], lbuf[2][32], mrand[32], lrand[32];

    const __bf16* qbase = Qb + ((long)b * HH + h) * TT * HD;
    const __bf16* kbase = Kb + ((long)b * HH + h) * TT * HD;
    const __bf16* vbase = Vb + ((long)b * HH + h) * TT * HD;
    const __bf16* vTbase = vT + ((long)b * HH + h) * HD * TT;

    // ---- S = Q K^T : MFMA with global fragments, S stays in registers ----
    bf16x8 aq[2];
    #pragma unroll
    for (int kk = 0; kk < 2; kk++)
        aq[kk] = *(const bf16x8*)(qbase + (long)(q0 + qh * 16 + fr) * HD + kk * 32 + fq * 8);

    f32x4 sc[6];
    #pragma unroll
    for (int t6 = 0; t6 < 6; t6++) {
        const int colg = (kr * 6 + t6) * 16 + fr;
        const int keyg = colg < 32 ? colg : lo + colg - 32;
        const int keyc = min(keyg, TT - 1);
        f32x4 c = {};
        #pragma unroll
        for (int kk = 0; kk < 2; kk++) {
            const bf16x8 bk = *(const bf16x8*)(kbase + (long)keyc * HD + kk * 32 + fq * 8);
            c = __builtin_amdgcn_mfma_f32_16x16x32_bf16(aq[kk], bk, c, 0, 0, 0);
        }
        sc[t6] = c;
    }

    // mask + scale + per-row max (rows fq*4+j of this wave's q-half)
    float rmax[4] = {-INFINITY, -INFINITY, -INFINITY, -INFINITY};
    #pragma unroll
    for (int t6 = 0; t6 < 6; t6++) {
        const int colg = (kr * 6 + t6) * 16 + fr;
        const int keyg = colg < 32 ? colg : lo + colg - 32;
        #pragma unroll
        for (int j = 0; j < 4; j++) {
            const int grow = q0 + qh * 16 + fq * 4 + j;
            const int dlt = keyg - grow;
            const bool valid = (colg < 32) || (keyg <= hi && dlt <= 64 && dlt >= -64);
            const float v = valid ? sc[t6][j] * 0.125f : -INFINITY;
            sc[t6][j] = v;
            rmax[j] = fmaxf(rmax[j], v);
        }
    }
    #pragma unroll
    for (int o = 1; o < 16; o <<= 1)
        #pragma unroll
        for (int j = 0; j < 4; j++)
            rmax[j] = fmaxf(rmax[j], __shfl_xor(rmax[j], o, 64));
    if (fr == 0)
        #pragma unroll
        for (int j = 0; j < 4; j++)
            mbuf[kr][qh * 16 + fq * 4 + j] = rmax[j];

    // ---- rand scores: thread (r = tid>>3, g = tid&7), coalesced gathers ----
    const int rr_r = tid >> 3;
    const int g = tid & 7;
    const int grow_r = q0 + rr_r;
    int crand[16];
    {
        const int4* rrv = (const int4*)(rand_idx + (long)grow_r * 16);
        #pragma unroll
        for (int c4 = 0; c4 < 4; c4++) {
            const int4 rv = rrv[c4];
            crand[c4 * 4 + 0] = rv.x; crand[c4 * 4 + 1] = rv.y;
            crand[c4 * 4 + 2] = rv.z; crand[c4 * 4 + 3] = rv.w;
        }
    }
    const bf16x8 q8 = *(const bf16x8*)(qbase + (long)grow_r * HD + g * 8);
    float srand[16];
    #pragma unroll
    for (int ch = 0; ch < 2; ch++) {
        bf16x8 kf[8];
        #pragma unroll
        for (int j = 0; j < 8; j++)
            kf[j] = *(const bf16x8*)(kbase + (long)max(crand[ch * 8 + j], 0) * HD + g * 8);
        #pragma unroll
        for (int j = 0; j < 8; j++) {
            float s = 0.f;
            #pragma unroll
            for (int e = 0; e < 8; e++) s += (float)q8[e] * (float)kf[j][e];
            s += __shfl_xor(s, 1, 64);
            s += __shfl_xor(s, 2, 64);
            s += __shfl_xor(s, 4, 64);
            srand[ch * 8 + j] = crand[ch * 8 + j] >= 0 ? s * 0.125f : -INFINITY;
        }
    }
    float mr = -INFINITY;
    #pragma unroll
    for (int j = 0; j < 16; j++) mr = fmaxf(mr, srand[j]);
    if (g == 0) mrand[rr_r] = mr;

    __syncthreads();   // barrier 1: m partials visible

    // ---- exp + row-sum + P writes (MFMA role) ----
    {
        float nm[4], lsum[4] = {};
        #pragma unroll
        for (int j = 0; j < 4; j++) {
            const int rl = qh * 16 + fq * 4 + j;
            nm[j] = fmaxf(fmaxf(mbuf[0][rl], mbuf[1][rl]), mrand[rl]);
        }
        #pragma unroll
        for (int t6 = 0; t6 < 6; t6++)
            #pragma unroll
            for (int j = 0; j < 4; j++) {
                const float p = __expf(sc[t6][j] - nm[j]);
                sc[t6][j] = p;
                lsum[j] += p;
            }
        #pragma unroll
        for (int o = 1; o < 16; o <<= 1)
            #pragma unroll
            for (int j = 0; j < 4; j++)
                lsum[j] += __shfl_xor(lsum[j], o, 64);
        if (fr == 0)
            #pragma unroll
            for (int j = 0; j < 4; j++)
                lbuf[kr][qh * 16 + fq * 4 + j] = lsum[j];
        #pragma unroll
        for (int t6 = 0; t6 < 6; t6++) {
            const int key = (kr * 6 + t6) * 16 + fr;
            #pragma unroll
            for (int j = 0; j < 4; j++) {
                const int rl = qh * 16 + fq * 4 + j;
                *(__bf16*)(Pmem + ((rl * PROWB + key * 2) ^ SW(rl))) = (__bf16)sc[t6][j];
            }
        }
    }

    // ---- rand p (rand role) ----
    float prand[16];
    {
        const float nmr = fmaxf(fmaxf(mbuf[0][rr_r], mbuf[1][rr_r]), mrand[rr_r]);
        float lr = 0.f;
        #pragma unroll
        for (int j = 0; j < 16; j++) {
            prand[j] = __expf(srand[j] - nmr);
            lr += prand[j];
        }
        if (g == 0) lrand[rr_r] = lr;
    }

    __syncthreads();   // barrier 2: P + l partials visible

    // ---- rand PV (rand role): coalesced bf16 V gathers ----
    float arand[8] = {};
    #pragma unroll
    for (int ch = 0; ch < 2; ch++) {
        bf16x8 vf[8];
        #pragma unroll
        for (int j = 0; j < 8; j++)
            vf[j] = *(const bf16x8*)(vbase + (long)max(crand[ch * 8 + j], 0) * HD + g * 8);
        #pragma unroll
        for (int j = 0; j < 8; j++) {
            const float p = prand[ch * 8 + j];
            #pragma unroll
            for (int e = 0; e < 8; e++) arand[e] += p * (float)vf[j][e];
        }
    }

    // ---- O = P V : MFMA, P from LDS, V^T fragments from global ----
    f32x4 ov[2] = {};
    {
        const int rl = qh * 16 + fr;
        #pragma unroll
        for (int t = 0; t < 6; t++) {
            const bf16x8 ap = *(const bf16x8*)(Pmem + ((rl * PROWB + (t * 32 + fq * 8) * 2) ^ SW(rl)));
            const int key0 = t * 32 + fq * 8;
            int tg = key0 < 32 ? key0 : lo + key0 - 32;
            tg = min(tg, TT - 8);
            #pragma unroll
            for (int ti = 0; ti < 2; ti++) {
                const int d = kr * 32 + ti * 16 + fr;
                const bf16x8 bv = *(const bf16x8*)(vTbase + (long)d * TT + tg);
                ov[ti] = __builtin_amdgcn_mfma_f32_16x16x32_bf16(ap, bv, ov[ti], 0, 0, 0);
            }
        }
    }

    __syncthreads();   // barrier 3: P reads done, alias Pmem as Obuf

    float* Ob = (float*)Pmem;   // 32 x 68 fp32
    #pragma unroll
    for (int ti = 0; ti < 2; ti++)
        #pragma unroll
        for (int j = 0; j < 4; j++)
            Ob[(qh * 16 + fq * 4 + j) * 68 + kr * 32 + ti * 16 + fr] = ov[ti][j];

    __syncthreads();   // barrier 4: Obuf visible

    {
        const float linv = 1.f /
            (lbuf[0][rr_r] + lbuf[1][rr_r] + lrand[rr_r]);
        bf16x8 o8;
        #pragma unroll
        for (int e = 0; e < 8; e++)
            o8[e] = (__bf16)((Ob[rr_r * 68 + g * 8 + e] + arand[e]) * linv);
        *(bf16x8*)(Ao + ((long)b * TT + grow_r) * DD + h * HD + g * 8) = o8;
    }
}

// ---------------------------------------------------------------------------
extern "C" void kernel_launch(void* const* d_in, const int* in_sizes, int n_in,
                              void* d_out, int out_size, void* d_ws, size_t ws_size,
                              hipStream_t stream)
{
    const float* x  = (const float*)d_in[0];
    const float* Wq = (const float*)d_in[1];
    const float* bq = (const float*)d_in[2];
    const float* Wk = (const float*)d_in[3];
    const float* bk = (const float*)d_in[4];
    const float* Wv = (const float*)d_in[5];
    const float* bv = (const float*)d_in[6];
    const float* Wo = (const float*)d_in[7];
    const float* bo = (const float*)d_in[8];
    const void*  mask = d_in[9];

    __bf16* xb   = (__bf16*)d_ws;
    __bf16* qkvb = xb + BTD;                  // q|k|v bf16, 3*BTD
    __bf16* vTb  = qkvb + 3 * BTD;
    __bf16* aob  = vTb + BTD;
    __bf16* Wcat = aob + BTD;
    __bf16* Wob  = Wcat + (long)3 * DD * DD;
    int*    rand_idx = (int*)(Wob + (long)DD * DD);
    float*  part = (float*)(rand_idx + (long)TT * 16);

    extract_rand<<<TT - 32, 64, 0, stream>>>(mask, rand_idx);

    const int WN4 = DD * DD / 4;
    cvt_bf16<<<(int)(BTD / 4 + 255) / 256, 256, 0, stream>>>(x, xb, (int)(BTD / 4));
    cvt_bf16<<<(WN4 + 255) / 256, 256, 0, stream>>>(Wq, Wcat, WN4);
    cvt_bf16<<<(WN4 + 255) / 256, 256, 0, stream>>>(Wk, Wcat + (long)DD * DD, WN4);
    cvt_bf16<<<(WN4 + 255) / 256, 256, 0, stream>>>(Wv, Wcat + (long)2 * DD * DD, WN4);
    cvt_bf16<<<(WN4 + 255) / 256, 256, 0, stream>>>(Wo, Wob, WN4);

    // QKV fused GEMM -> bf16 q|k|v (head layout)
    mfma_gemm<<<dim3(3 * DD / 128, MM / 128), 256, 0, stream>>>(
        xb, Wcat, bq, bk, bv, nullptr, qkvb, 3 * DD, 1);

    vt_transpose<<<dim3(TT / 64, HH, BB), 256, 0, stream>>>(qkvb + 2 * BTD, vTb);

    bb_dense_rows<<<dim3(8, HH, BB), 256, 0, stream>>>(
        qkvb, qkvb + BTD, qkvb + 2 * BTD, part);
    bb_dense_combine<<<dim3(HH, BB), 256, 0, stream>>>(part, aob);

    bb_sparse2<<<dim3(TT / 32 - 1, HH, BB), 256, 0, stream>>>(
        qkvb, qkvb + BTD, qkvb + 2 * BTD, vTb, rand_idx, aob);

    mfma_gemm<<<dim3(DD / 128, MM / 128), 256, 0, stream>>>(
        aob, Wob, bo, bo, bo, (float*)d_out, nullptr, DD, 0);
}

// Round 6
// 140.504 us; speedup vs baseline: 2.2418x; 1.2877x over previous
//
#include <hip/hip_runtime.h>
#include <hip/hip_bf16.h>
#include <math.h>

#define BB   2
#define TT   2048
#define DD   768
#define HH   12
#define HD   64
#define MM   (BB*TT)
#define BTD  ((long)BB*TT*DD)

typedef __bf16 bf16x8 __attribute__((ext_vector_type(8)));
typedef __bf16 bf16x4 __attribute__((ext_vector_type(4)));
typedef float  f32x4  __attribute__((ext_vector_type(4)));

// ---------------------------------------------------------------------------
// fp32 -> bf16 convert (x)
// ---------------------------------------------------------------------------
__global__ __launch_bounds__(256) void cvt_bf16(
    const float* __restrict__ in, __bf16* __restrict__ out, int n4)
{
    const int i = blockIdx.x * 256 + threadIdx.x;
    if (i < n4) {
        const float4 v = ((const float4*)in)[i];
        bf16x4 o;
        o.x = (__bf16)v.x; o.y = (__bf16)v.y;
        o.z = (__bf16)v.z; o.w = (__bf16)v.w;
        ((bf16x4*)out)[i] = o;
    }
}

// all 4 weight matrices in one launch: seg = blockIdx.y
__global__ __launch_bounds__(256) void cvt_w4(
    const float* __restrict__ w0, const float* __restrict__ w1,
    const float* __restrict__ w2, const float* __restrict__ w3,
    __bf16* __restrict__ Wcat, __bf16* __restrict__ Wob)
{
    const int seg = blockIdx.y;
    const int i = blockIdx.x * 256 + threadIdx.x;
    const int n4 = DD * DD / 4;
    if (i >= n4) return;
    const float* src = seg == 0 ? w0 : seg == 1 ? w1 : seg == 2 ? w2 : w3;
    __bf16* dst = seg < 3 ? Wcat + (long)seg * DD * DD : Wob;
    const float4 v = ((const float4*)src)[i];
    bf16x4 o;
    o.x = (__bf16)v.x; o.y = (__bf16)v.y;
    o.z = (__bf16)v.z; o.w = (__bf16)v.w;
    ((bf16x4*)dst)[i] = o;
}

// ---------------------------------------------------------------------------
// bf16 MFMA GEMM: Y = A @ B^T + bias.  2-phase double-buffered staging +
// XCD-aware block swizzle (nwg % 8 == 0 for both launches).
//   mode 0: fp32 Y row-major (N=768)
//   mode 1: N=2304 -> bf16 q|k|v in (B,H,T,HD) layout (Yb base, 3*BTD)
// ---------------------------------------------------------------------------
__global__ __launch_bounds__(256) void mfma_gemm(
    const __bf16* __restrict__ A, const __bf16* __restrict__ Bw,
    const float* __restrict__ b0, const float* __restrict__ b1,
    const float* __restrict__ b2, float* __restrict__ Y,
    __bf16* __restrict__ Yb, int N, int mode)
{
    constexpr int K = DD;
    constexpr int NT = K / 32;               // 24 K-steps
    __shared__ __bf16 As[2][128 * 32];
    __shared__ __bf16 Bs[2][128 * 32];

    const int tid  = threadIdx.x;
    const int wid  = tid >> 6, lane = tid & 63;
    const int fq = lane >> 4, fr = lane & 15;
    const int wr = wid >> 1, wc = wid & 1;

    // XCD swizzle: consecutive logical tiles land on the same XCD's L2
    const int gx = gridDim.x;
    const int nwg = gx * gridDim.y;
    const int bid = blockIdx.y * gx + blockIdx.x;
    const int cpx = nwg >> 3;
    const int swz = (bid & 7) * cpx + (bid >> 3);
    const int m0 = (swz / gx) * 128, n0 = (swz % gx) * 128;

    f32x4 acc[4][4] = {};

    const char* Ag = (const char*)(A + (long)m0 * K);
    const char* Bg = (const char*)(Bw + (long)n0 * K);

    auto stage = [&](int buf, int k0) {
        #pragma unroll
        for (int c = 0; c < 2; c++) {
            const int o   = wid * 2048 + c * 1024 + lane * 16;
            const int row = o >> 6, kb = o & 63;
            const long goff = (long)row * (K * 2) + k0 * 2 + kb;
            __builtin_amdgcn_global_load_lds(
                (const __attribute__((address_space(1))) void*)(Ag + goff),
                (__attribute__((address_space(3))) void*)((char*)As[buf] + wid * 2048 + c * 1024),
                16, 0, 0);
            __builtin_amdgcn_global_load_lds(
                (const __attribute__((address_space(1))) void*)(Bg + goff),
                (__attribute__((address_space(3))) void*)((char*)Bs[buf] + wid * 2048 + c * 1024),
                16, 0, 0);
        }
    };

    auto compute = [&](int buf) {
        bf16x8 af[4], bfr[4];
        #pragma unroll
        for (int m = 0; m < 4; m++)
            af[m] = *(const bf16x8*)(As[buf] + ((wr * 64 + m * 16 + fr) * 32 + fq * 8));
        #pragma unroll
        for (int n = 0; n < 4; n++)
            bfr[n] = *(const bf16x8*)(Bs[buf] + ((wc * 64 + n * 16 + fr) * 32 + fq * 8));
        #pragma unroll
        for (int m = 0; m < 4; m++)
            #pragma unroll
            for (int n = 0; n < 4; n++)
                acc[m][n] = __builtin_amdgcn_mfma_f32_16x16x32_bf16(
                    af[m], bfr[n], acc[m][n], 0, 0, 0);
    };

    // 2-phase: prefetch next tile before computing current; 1 barrier/iter
    int cur = 0;
    stage(0, 0);
    __syncthreads();
    for (int t = 0; t < NT - 1; ++t) {
        stage(cur ^ 1, (t + 1) * 32);
        compute(cur);
        __syncthreads();     // implicit vmcnt(0)+lgkmcnt(0) drain
        cur ^= 1;
    }
    compute(cur);            // last tile, no prefetch

    #pragma unroll
    for (int m = 0; m < 4; m++) {
        const int grow = m0 + wr * 64 + m * 16 + fq * 4;
        #pragma unroll
        for (int n = 0; n < 4; n++) {
            const int col = n0 + wc * 64 + n * 16 + fr;
            if (mode == 0) {
                const float bias = b0[col];
                #pragma unroll
                for (int j = 0; j < 4; j++)
                    Y[(long)(grow + j) * N + col] = acc[m][n][j] + bias;
            } else {
                const int which = col / DD;
                const int nn = col - which * DD;
                const float* bp = which == 0 ? b0 : (which == 1 ? b1 : b2);
                const float bias = bp[nn];
                const int h_ = nn >> 6, d_ = nn & 63;
                __bf16* baseb = Yb + (long)which * BTD;
                #pragma unroll
                for (int j = 0; j < 4; j++) {
                    const int row = grow + j;
                    const int b_ = row >> 11, t_ = row & (TT - 1);
                    baseb[(((long)b_ * HH + h_) * TT + t_) * HD + d_] =
                        (__bf16)(acc[m][n][j] + bias);
                }
            }
        }
    }
}

// ---------------------------------------------------------------------------
// v bf16 (b,h,t,d) -> vT bf16 (b,h,d,t)
// ---------------------------------------------------------------------------
__global__ __launch_bounds__(256) void vt_transpose(
    const __bf16* __restrict__ V, __bf16* __restrict__ vT)
{
    const int t0 = blockIdx.x * 64, h = blockIdx.y, b = blockIdx.z;
    const int tid = threadIdx.x;
    __shared__ float tl[64][65];
    const __bf16* vb = V + (((long)b * HH + h) * TT + t0) * HD;
    for (int i = tid; i < 64 * 64; i += 256)
        tl[i >> 6][i & 63] = (float)vb[i];
    __syncthreads();
    __bf16* ob = vT + ((long)b * HH + h) * HD * TT + t0;
    for (int i = tid; i < 64 * 64; i += 256) {
        const int d = i >> 6, t = i & 63;
        ob[(long)d * TT + t] = (__bf16)tl[t][d];
    }
}

// ---------------------------------------------------------------------------
// Extract the 16 random key columns per row (rows 32..2047).
// ---------------------------------------------------------------------------
__global__ __launch_bounds__(64) void extract_rand(
    const void* __restrict__ maskp, int* __restrict__ rand_idx)
{
    const int row = blockIdx.x + 32;
    const int lane = threadIdx.x;
    const unsigned char* m8 = (const unsigned char*)maskp;
    const int* m32 = (const int*)maskp;
    const bool u8 = (m8[1] != 0);

    int loc[16];
    int cnt = 0;
    const int c0 = lane * 32;
    for (int t = 0; t < 32; t++) {
        int c = c0 + t;
        int d = c - row;
        if (c >= 32 && (d > 64 || d < -64)) {
            int mv = u8 ? (int)m8[(long)row * TT + c] : m32[(long)row * TT + c];
            if (mv && cnt < 16) loc[cnt++] = c;
        }
    }
    int incl = cnt;
    for (int d = 1; d < 64; d <<= 1) {
        int n = __shfl_up(incl, d, 64);
        if (lane >= d) incl += n;
    }
    const int excl = incl - cnt;
    for (int i = 0; i < cnt; i++) {
        int p = excl + i;
        if (p < 16) rand_idx[(long)row * 16 + p] = loc[i];
    }
    const int total = __shfl(incl, 63, 64);
    if (lane == 0)
        for (int p = total; p < 16; p++) rand_idx[(long)row * 16 + p] = -1;
}

// ---------------------------------------------------------------------------
// Dense rows 0..31, MFMA flash partials over 256-key chunks (8 chunks).
// Zero-staging: Q/K/V^T fragments straight from global (L2-resident).
// part: [(b*H+h)][ch(8)][row(32)][66] = {m, l, acc[64]} unnormalized.
// ---------------------------------------------------------------------------
#define DPROWB 512   // P row stride bytes (256 bf16)
#define SW(r) (((r) & 7) << 4)

__global__ __launch_bounds__(256) void bb_dense2(
    const __bf16* __restrict__ Qb, const __bf16* __restrict__ Kb,
    const __bf16* __restrict__ vT, float* __restrict__ part)
{
    const int ch = blockIdx.x, h = blockIdx.y, b = blockIdx.z;
    const int tid = threadIdx.x;
    const int w = tid >> 6, lane = tid & 63;
    const int fq = lane >> 4, fr = lane & 15;
    const int qh = w & 1, kr = w >> 1;
    const int k0 = ch * 256;

    __shared__ __attribute__((aligned(16))) char Pmem[32 * DPROWB]; // P; later Obuf f32[32][68]
    __shared__ float mbuf[2][32], lbuf[2][32];

    const __bf16* qbase = Qb + ((long)b * HH + h) * TT * HD;   // rows 0..31
    const __bf16* kbase = Kb + ((long)b * HH + h) * TT * HD;
    const __bf16* vTbase = vT + ((long)b * HH + h) * HD * TT;

    // ---- S = Q K^T (8 col-tiles of 16 per wave) ----
    bf16x8 aq[2];
    #pragma unroll
    for (int kk = 0; kk < 2; kk++)
        aq[kk] = *(const bf16x8*)(qbase + (long)(qh * 16 + fr) * HD + kk * 32 + fq * 8);

    f32x4 sc[8];
    #pragma unroll
    for (int t = 0; t < 8; t++) {
        const int key = k0 + (kr * 8 + t) * 16 + fr;
        f32x4 c = {};
        #pragma unroll
        for (int kk = 0; kk < 2; kk++) {
            const bf16x8 bk = *(const bf16x8*)(kbase + (long)key * HD + kk * 32 + fq * 8);
            c = __builtin_amdgcn_mfma_f32_16x16x32_bf16(aq[kk], bk, c, 0, 0, 0);
        }
        sc[t] = c;
    }

    float rmax[4] = {-INFINITY, -INFINITY, -INFINITY, -INFINITY};
    #pragma unroll
    for (int t = 0; t < 8; t++)
        #pragma unroll
        for (int j = 0; j < 4; j++) {
            sc[t][j] *= 0.125f;
            rmax[j] = fmaxf(rmax[j], sc[t][j]);
        }
    #pragma unroll
    for (int o = 1; o < 16; o <<= 1)
        #pragma unroll
        for (int j = 0; j < 4; j++)
            rmax[j] = fmaxf(rmax[j], __shfl_xor(rmax[j], o, 64));
    if (fr == 0)
        #pragma unroll
        for (int j = 0; j < 4; j++)
            mbuf[kr][qh * 16 + fq * 4 + j] = rmax[j];

    __syncthreads();

    // ---- exp + row-sum + P writes ----
    {
        float nm[4], lsum[4] = {};
        #pragma unroll
        for (int j = 0; j < 4; j++) {
            const int rl = qh * 16 + fq * 4 + j;
            nm[j] = fmaxf(mbuf[0][rl], mbuf[1][rl]);
        }
        #pragma unroll
        for (int t = 0; t < 8; t++)
            #pragma unroll
            for (int j = 0; j < 4; j++) {
                const float p = __expf(sc[t][j] - nm[j]);
                sc[t][j] = p;
                lsum[j] += p;
            }
        #pragma unroll
        for (int o = 1; o < 16; o <<= 1)
            #pragma unroll
            for (int j = 0; j < 4; j++)
                lsum[j] += __shfl_xor(lsum[j], o, 64);
        if (fr == 0)
            #pragma unroll
            for (int j = 0; j < 4; j++)
                lbuf[kr][qh * 16 + fq * 4 + j] = lsum[j];
        #pragma unroll
        for (int t = 0; t < 8; t++) {
            const int colc = (kr * 8 + t) * 16 + fr;
            #pragma unroll
            for (int j = 0; j < 4; j++) {
                const int rl = qh * 16 + fq * 4 + j;
                *(__bf16*)(Pmem + ((rl * DPROWB + colc * 2) ^ SW(rl))) = (__bf16)sc[t][j];
            }
        }
    }
    __syncthreads();

    // ---- O = P V (per wave: 16 rows x 32 d, 8 K-steps of 32 keys) ----
    f32x4 ov[2] = {};
    {
        const int rl = qh * 16 + fr;
        #pragma unroll
        for (int t = 0; t < 8; t++) {
            const bf16x8 ap = *(const bf16x8*)(Pmem + ((rl * DPROWB + (t * 32 + fq * 8) * 2) ^ SW(rl)));
            #pragma unroll
            for (int ti = 0; ti < 2; ti++) {
                const int d = kr * 32 + ti * 16 + fr;
                const bf16x8 bv = *(const bf16x8*)(vTbase + (long)d * TT + k0 + t * 32 + fq * 8);
                ov[ti] = __builtin_amdgcn_mfma_f32_16x16x32_bf16(ap, bv, ov[ti], 0, 0, 0);
            }
        }
    }
    __syncthreads();   // P reads done; alias Pmem as Obuf

    float* Ob = (float*)Pmem;   // 32 x 68
    #pragma unroll
    for (int ti = 0; ti < 2; ti++)
        #pragma unroll
        for (int j = 0; j < 4; j++)
            Ob[(qh * 16 + fq * 4 + j) * 68 + kr * 32 + ti * 16 + fr] = ov[ti][j];
    __syncthreads();

    {
        const int r = tid >> 3, g = tid & 7;
        float* pb = part + ((((long)b * HH + h) * 8 + ch) * 32 + r) * 66;
        if (g == 0) {
            pb[0] = fmaxf(mbuf[0][r], mbuf[1][r]);
            pb[1] = lbuf[0][r] + lbuf[1][r];
        }
        #pragma unroll
        for (int e = 0; e < 8; e++)
            pb[2 + g * 8 + e] = Ob[r * 68 + g * 8 + e];
    }
}

__global__ __launch_bounds__(256) void bb_dense_combine(
    const float* __restrict__ part, __bf16* __restrict__ Ao)
{
    const int h = blockIdx.x, b = blockIdx.y;
    const int tid = threadIdx.x;
    const int r = tid >> 3, dsl = (tid & 7) * 8;
    const float* pb = part + (((long)b * HH + h) * 8 * 32 + r) * 66;
    float M = -INFINITY;
    #pragma unroll
    for (int c = 0; c < 8; c++) M = fmaxf(M, pb[(long)c * 32 * 66]);
    float L = 0.f, o[8] = {};
    #pragma unroll
    for (int c = 0; c < 8; c++) {
        const float* pc = pb + (long)c * 32 * 66;
        const float w = __expf(pc[0] - M);
        L += w * pc[1];
        #pragma unroll
        for (int j = 0; j < 8; j++) o[j] += w * pc[2 + dsl + j];
    }
    const float inv = 1.f / L;
    const long ob = ((long)b * TT + r) * DD + h * HD + dsl;
    #pragma unroll
    for (int j = 0; j < 8; j++) Ao[ob + j] = (__bf16)(o[j] * inv);
}

// ---------------------------------------------------------------------------
// Sparse rows 32..2047 (unchanged from round 5).
// ---------------------------------------------------------------------------
#define PROWB 384

__global__ __launch_bounds__(256) void bb_sparse2(
    const __bf16* __restrict__ Qb, const __bf16* __restrict__ Kb,
    const __bf16* __restrict__ Vb, const __bf16* __restrict__ vT,
    const int* __restrict__ rand_idx, __bf16* __restrict__ Ao)
{
    const int q0 = (blockIdx.x + 1) * 32;
    const int h = blockIdx.y, b = blockIdx.z;
    const int tid = threadIdx.x;
    const int w = tid >> 6, lane = tid & 63;
    const int fq = lane >> 4, fr = lane & 15;
    const int qh = w & 1, kr = w >> 1;

    const int lo = max(32, q0 - 64);
    const int hi = min(TT - 1, q0 + 95);

    __shared__ __attribute__((aligned(16))) char Pmem[32 * PROWB];
    __shared__ float mbuf[2][32], lbuf[2][32], mrand[32], lrand[32];

    const __bf16* qbase = Qb + ((long)b * HH + h) * TT * HD;
    const __bf16* kbase = Kb + ((long)b * HH + h) * TT * HD;
    const __bf16* vbase = Vb + ((long)b * HH + h) * TT * HD;
    const __bf16* vTbase = vT + ((long)b * HH + h) * HD * TT;

    bf16x8 aq[2];
    #pragma unroll
    for (int kk = 0; kk < 2; kk++)
        aq[kk] = *(const bf16x8*)(qbase + (long)(q0 + qh * 16 + fr) * HD + kk * 32 + fq * 8);

    f32x4 sc[6];
    #pragma unroll
    for (int t6 = 0; t6 < 6; t6++) {
        const int colg = (kr * 6 + t6) * 16 + fr;
        const int keyg = colg < 32 ? colg : lo + colg - 32;
        const int keyc = min(keyg, TT - 1);
        f32x4 c = {};
        #pragma unroll
        for (int kk = 0; kk < 2; kk++) {
            const bf16x8 bk = *(const bf16x8*)(kbase + (long)keyc * HD + kk * 32 + fq * 8);
            c = __builtin_amdgcn_mfma_f32_16x16x32_bf16(aq[kk], bk, c, 0, 0, 0);
        }
        sc[t6] = c;
    }

    float rmax[4] = {-INFINITY, -INFINITY, -INFINITY, -INFINITY};
    #pragma unroll
    for (int t6 = 0; t6 < 6; t6++) {
        const int colg = (kr * 6 + t6) * 16 + fr;
        const int keyg = colg < 32 ? colg : lo + colg - 32;
        #pragma unroll
        for (int j = 0; j < 4; j++) {
            const int grow = q0 + qh * 16 + fq * 4 + j;
            const int dlt = keyg - grow;
            const bool valid = (colg < 32) || (keyg <= hi && dlt <= 64 && dlt >= -64);
            const float v = valid ? sc[t6][j] * 0.125f : -INFINITY;
            sc[t6][j] = v;
            rmax[j] = fmaxf(rmax[j], v);
        }
    }
    #pragma unroll
    for (int o = 1; o < 16; o <<= 1)
        #pragma unroll
        for (int j = 0; j < 4; j++)
            rmax[j] = fmaxf(rmax[j], __shfl_xor(rmax[j], o, 64));
    if (fr == 0)
        #pragma unroll
        for (int j = 0; j < 4; j++)
            mbuf[kr][qh * 16 + fq * 4 + j] = rmax[j];

    const int rr_r = tid >> 3;
    const int g = tid & 7;
    const int grow_r = q0 + rr_r;
    int crand[16];
    {
        const int4* rrv = (const int4*)(rand_idx + (long)grow_r * 16);
        #pragma unroll
        for (int c4 = 0; c4 < 4; c4++) {
            const int4 rv = rrv[c4];
            crand[c4 * 4 + 0] = rv.x; crand[c4 * 4 + 1] = rv.y;
            crand[c4 * 4 + 2] = rv.z; crand[c4 * 4 + 3] = rv.w;
        }
    }
    const bf16x8 q8 = *(const bf16x8*)(qbase + (long)grow_r * HD + g * 8);
    float srand[16];
    #pragma unroll
    for (int ch = 0; ch < 2; ch++) {
        bf16x8 kf[8];
        #pragma unroll
        for (int j = 0; j < 8; j++)
            kf[j] = *(const bf16x8*)(kbase + (long)max(crand[ch * 8 + j], 0) * HD + g * 8);
        #pragma unroll
        for (int j = 0; j < 8; j++) {
            float s = 0.f;
            #pragma unroll
            for (int e = 0; e < 8; e++) s += (float)q8[e] * (float)kf[j][e];
            s += __shfl_xor(s, 1, 64);
            s += __shfl_xor(s, 2, 64);
            s += __shfl_xor(s, 4, 64);
            srand[ch * 8 + j] = crand[ch * 8 + j] >= 0 ? s * 0.125f : -INFINITY;
        }
    }
    float mr = -INFINITY;
    #pragma unroll
    for (int j = 0; j < 16; j++) mr = fmaxf(mr, srand[j]);
    if (g == 0) mrand[rr_r] = mr;

    __syncthreads();

    {
        float nm[4], lsum[4] = {};
        #pragma unroll
        for (int j = 0; j < 4; j++) {
            const int rl = qh * 16 + fq * 4 + j;
            nm[j] = fmaxf(fmaxf(mbuf[0][rl], mbuf[1][rl]), mrand[rl]);
        }
        #pragma unroll
        for (int t6 = 0; t6 < 6; t6++)
            #pragma unroll
            for (int j = 0; j < 4; j++) {
                const float p = __expf(sc[t6][j] - nm[j]);
                sc[t6][j] = p;
                lsum[j] += p;
            }
        #pragma unroll
        for (int o = 1; o < 16; o <<= 1)
            #pragma unroll
            for (int j = 0; j < 4; j++)
                lsum[j] += __shfl_xor(lsum[j], o, 64);
        if (fr == 0)
            #pragma unroll
            for (int j = 0; j < 4; j++)
                lbuf[kr][qh * 16 + fq * 4 + j] = lsum[j];
        #pragma unroll
        for (int t6 = 0; t6 < 6; t6++) {
            const int key = (kr * 6 + t6) * 16 + fr;
            #pragma unroll
            for (int j = 0; j < 4; j++) {
                const int rl = qh * 16 + fq * 4 + j;
                *(__bf16*)(Pmem + ((rl * PROWB + key * 2) ^ SW(rl))) = (__bf16)sc[t6][j];
            }
        }
    }

    float prand[16];
    {
        const float nmr = fmaxf(fmaxf(mbuf[0][rr_r], mbuf[1][rr_r]), mrand[rr_r]);
        float lr = 0.f;
        #pragma unroll
        for (int j = 0; j < 16; j++) {
            prand[j] = __expf(srand[j] - nmr);
            lr += prand[j];
        }
        if (g == 0) lrand[rr_r] = lr;
    }

    __syncthreads();

    float arand[8] = {};
    #pragma unroll
    for (int ch = 0; ch < 2; ch++) {
        bf16x8 vf[8];
        #pragma unroll
        for (int j = 0; j < 8; j++)
            vf[j] = *(const bf16x8*)(vbase + (long)max(crand[ch * 8 + j], 0) * HD + g * 8);
        #pragma unroll
        for (int j = 0; j < 8; j++) {
            const float p = prand[ch * 8 + j];
            #pragma unroll
            for (int e = 0; e < 8; e++) arand[e] += p * (float)vf[j][e];
        }
    }

    f32x4 ov[2] = {};
    {
        const int rl = qh * 16 + fr;
        #pragma unroll
        for (int t = 0; t < 6; t++) {
            const bf16x8 ap = *(const bf16x8*)(Pmem + ((rl * PROWB + (t * 32 + fq * 8) * 2) ^ SW(rl)));
            const int key0 = t * 32 + fq * 8;
            int tg = key0 < 32 ? key0 : lo + key0 - 32;
            tg = min(tg, TT - 8);
            #pragma unroll
            for (int ti = 0; ti < 2; ti++) {
                const int d = kr * 32 + ti * 16 + fr;
                const bf16x8 bv = *(const bf16x8*)(vTbase + (long)d * TT + tg);
                ov[ti] = __builtin_amdgcn_mfma_f32_16x16x32_bf16(ap, bv, ov[ti], 0, 0, 0);
            }
        }
    }

    __syncthreads();

    float* Ob = (float*)Pmem;
    #pragma unroll
    for (int ti = 0; ti < 2; ti++)
        #pragma unroll
        for (int j = 0; j < 4; j++)
            Ob[(qh * 16 + fq * 4 + j) * 68 + kr * 32 + ti * 16 + fr] = ov[ti][j];

    __syncthreads();

    {
        const float linv = 1.f /
            (lbuf[0][rr_r] + lbuf[1][rr_r] + lrand[rr_r]);
        bf16x8 o8;
        #pragma unroll
        for (int e = 0; e < 8; e++)
            o8[e] = (__bf16)((Ob[rr_r * 68 + g * 8 + e] + arand[e]) * linv);
        *(bf16x8*)(Ao + ((long)b * TT + grow_r) * DD + h * HD + g * 8) = o8;
    }
}

// ---------------------------------------------------------------------------
extern "C" void kernel_launch(void* const* d_in, const int* in_sizes, int n_in,
                              void* d_out, int out_size, void* d_ws, size_t ws_size,
                              hipStream_t stream)
{
    const float* x  = (const float*)d_in[0];
    const float* Wq = (const float*)d_in[1];
    const float* bq = (const float*)d_in[2];
    const float* Wk = (const float*)d_in[3];
    const float* bk = (const float*)d_in[4];
    const float* Wv = (const float*)d_in[5];
    const float* bv = (const float*)d_in[6];
    const float* Wo = (const float*)d_in[7];
    const float* bo = (const float*)d_in[8];
    const void*  mask = d_in[9];

    __bf16* xb   = (__bf16*)d_ws;
    __bf16* qkvb = xb + BTD;                  // q|k|v bf16, 3*BTD
    __bf16* vTb  = qkvb + 3 * BTD;
    __bf16* aob  = vTb + BTD;
    __bf16* Wcat = aob + BTD;
    __bf16* Wob  = Wcat + (long)3 * DD * DD;
    int*    rand_idx = (int*)(Wob + (long)DD * DD);
    float*  part = (float*)(rand_idx + (long)TT * 16);

    extract_rand<<<TT - 32, 64, 0, stream>>>(mask, rand_idx);

    const int WN4 = DD * DD / 4;
    cvt_bf16<<<(int)(BTD / 4 + 255) / 256, 256, 0, stream>>>(x, xb, (int)(BTD / 4));
    cvt_w4<<<dim3((WN4 + 255) / 256, 4), 256, 0, stream>>>(Wq, Wk, Wv, Wo, Wcat, Wob);

    // QKV fused GEMM -> bf16 q|k|v (head layout)
    mfma_gemm<<<dim3(3 * DD / 128, MM / 128), 256, 0, stream>>>(
        xb, Wcat, bq, bk, bv, nullptr, qkvb, 3 * DD, 1);

    vt_transpose<<<dim3(TT / 64, HH, BB), 256, 0, stream>>>(qkvb + 2 * BTD, vTb);

    bb_dense2<<<dim3(8, HH, BB), 256, 0, stream>>>(
        qkvb, qkvb + BTD, vTb, part);
    bb_dense_combine<<<dim3(HH, BB), 256, 0, stream>>>(part, aob);

    bb_sparse2<<<dim3(TT / 32 - 1, HH, BB), 256, 0, stream>>>(
        qkvb, qkvb + BTD, qkvb + 2 * BTD, vTb, rand_idx, aob);

    mfma_gemm<<<dim3(DD / 128, MM / 128), 256, 0, stream>>>(
        aob, Wob, bo, bo, bo, (float*)d_out, nullptr, DD, 0);
}

// Round 7
// 132.236 us; speedup vs baseline: 2.3820x; 1.0625x over previous
//
#include <hip/hip_runtime.h>
#include <hip/hip_bf16.h>
#include <math.h>

#define BB   2
#define TT   2048
#define DD   768
#define HH   12
#define HD   64
#define MM   (BB*TT)
#define BTD  ((long)BB*TT*DD)

typedef __bf16 bf16x8 __attribute__((ext_vector_type(8)));
typedef __bf16 bf16x4 __attribute__((ext_vector_type(4)));
typedef float  f32x4  __attribute__((ext_vector_type(4)));

// ---------------------------------------------------------------------------
// fp32 -> bf16 convert (x)
// ---------------------------------------------------------------------------
__global__ __launch_bounds__(256) void cvt_bf16(
    const float* __restrict__ in, __bf16* __restrict__ out, int n4)
{
    const int i = blockIdx.x * 256 + threadIdx.x;
    if (i < n4) {
        const float4 v = ((const float4*)in)[i];
        bf16x4 o;
        o.x = (__bf16)v.x; o.y = (__bf16)v.y;
        o.z = (__bf16)v.z; o.w = (__bf16)v.w;
        ((bf16x4*)out)[i] = o;
    }
}

// all 4 weight matrices in one launch: seg = blockIdx.y
__global__ __launch_bounds__(256) void cvt_w4(
    const float* __restrict__ w0, const float* __restrict__ w1,
    const float* __restrict__ w2, const float* __restrict__ w3,
    __bf16* __restrict__ Wcat, __bf16* __restrict__ Wob)
{
    const int seg = blockIdx.y;
    const int i = blockIdx.x * 256 + threadIdx.x;
    const int n4 = DD * DD / 4;
    if (i >= n4) return;
    const float* src = seg == 0 ? w0 : seg == 1 ? w1 : seg == 2 ? w2 : w3;
    __bf16* dst = seg < 3 ? Wcat + (long)seg * DD * DD : Wob;
    const float4 v = ((const float4*)src)[i];
    bf16x4 o;
    o.x = (__bf16)v.x; o.y = (__bf16)v.y;
    o.z = (__bf16)v.z; o.w = (__bf16)v.w;
    ((bf16x4*)dst)[i] = o;
}

// ---------------------------------------------------------------------------
// bf16 MFMA GEMM: Y = A @ B^T + bias.  2-phase double-buffered staging +
// XCD-aware block swizzle.
// ---------------------------------------------------------------------------
__global__ __launch_bounds__(256) void mfma_gemm(
    const __bf16* __restrict__ A, const __bf16* __restrict__ Bw,
    const float* __restrict__ b0, const float* __restrict__ b1,
    const float* __restrict__ b2, float* __restrict__ Y,
    __bf16* __restrict__ Yb, int N, int mode)
{
    constexpr int K = DD;
    constexpr int NT = K / 32;               // 24 K-steps
    __shared__ __bf16 As[2][128 * 32];
    __shared__ __bf16 Bs[2][128 * 32];

    const int tid  = threadIdx.x;
    const int wid  = tid >> 6, lane = tid & 63;
    const int fq = lane >> 4, fr = lane & 15;
    const int wr = wid >> 1, wc = wid & 1;

    const int gx = gridDim.x;
    const int nwg = gx * gridDim.y;
    const int bid = blockIdx.y * gx + blockIdx.x;
    const int cpx = nwg >> 3;
    const int swz = (bid & 7) * cpx + (bid >> 3);
    const int m0 = (swz / gx) * 128, n0 = (swz % gx) * 128;

    f32x4 acc[4][4] = {};

    const char* Ag = (const char*)(A + (long)m0 * K);
    const char* Bg = (const char*)(Bw + (long)n0 * K);

    auto stage = [&](int buf, int k0) {
        #pragma unroll
        for (int c = 0; c < 2; c++) {
            const int o   = wid * 2048 + c * 1024 + lane * 16;
            const int row = o >> 6, kb = o & 63;
            const long goff = (long)row * (K * 2) + k0 * 2 + kb;
            __builtin_amdgcn_global_load_lds(
                (const __attribute__((address_space(1))) void*)(Ag + goff),
                (__attribute__((address_space(3))) void*)((char*)As[buf] + wid * 2048 + c * 1024),
                16, 0, 0);
            __builtin_amdgcn_global_load_lds(
                (const __attribute__((address_space(1))) void*)(Bg + goff),
                (__attribute__((address_space(3))) void*)((char*)Bs[buf] + wid * 2048 + c * 1024),
                16, 0, 0);
        }
    };

    auto compute = [&](int buf) {
        bf16x8 af[4], bfr[4];
        #pragma unroll
        for (int m = 0; m < 4; m++)
            af[m] = *(const bf16x8*)(As[buf] + ((wr * 64 + m * 16 + fr) * 32 + fq * 8));
        #pragma unroll
        for (int n = 0; n < 4; n++)
            bfr[n] = *(const bf16x8*)(Bs[buf] + ((wc * 64 + n * 16 + fr) * 32 + fq * 8));
        #pragma unroll
        for (int m = 0; m < 4; m++)
            #pragma unroll
            for (int n = 0; n < 4; n++)
                acc[m][n] = __builtin_amdgcn_mfma_f32_16x16x32_bf16(
                    af[m], bfr[n], acc[m][n], 0, 0, 0);
    };

    int cur = 0;
    stage(0, 0);
    __syncthreads();
    for (int t = 0; t < NT - 1; ++t) {
        stage(cur ^ 1, (t + 1) * 32);
        compute(cur);
        __syncthreads();
        cur ^= 1;
    }
    compute(cur);

    #pragma unroll
    for (int m = 0; m < 4; m++) {
        const int grow = m0 + wr * 64 + m * 16 + fq * 4;
        #pragma unroll
        for (int n = 0; n < 4; n++) {
            const int col = n0 + wc * 64 + n * 16 + fr;
            if (mode == 0) {
                const float bias = b0[col];
                #pragma unroll
                for (int j = 0; j < 4; j++)
                    Y[(long)(grow + j) * N + col] = acc[m][n][j] + bias;
            } else {
                const int which = col / DD;
                const int nn = col - which * DD;
                const float* bp = which == 0 ? b0 : (which == 1 ? b1 : b2);
                const float bias = bp[nn];
                const int h_ = nn >> 6, d_ = nn & 63;
                __bf16* baseb = Yb + (long)which * BTD;
                #pragma unroll
                for (int j = 0; j < 4; j++) {
                    const int row = grow + j;
                    const int b_ = row >> 11, t_ = row & (TT - 1);
                    baseb[(((long)b_ * HH + h_) * TT + t_) * HD + d_] =
                        (__bf16)(acc[m][n][j] + bias);
                }
            }
        }
    }
}

// ---------------------------------------------------------------------------
// v bf16 (b,h,t,d) -> vT bf16 (b,h,d,t); XCD-pinned 1D grid (768 blocks)
// ---------------------------------------------------------------------------
__global__ __launch_bounds__(256) void vt_transpose(
    const __bf16* __restrict__ V, __bf16* __restrict__ vT)
{
    const int bid = blockIdx.x;
    const int xcd = bid & 7;
    const int idx = bid >> 3;           // 0..95
    const int gsel = idx >> 5;          // 0..2
    const int t0 = (idx & 31) * 64;
    const int grp = xcd + 8 * gsel;     // b*HH+h
    const int b = grp / HH, h = grp % HH;

    const int tid = threadIdx.x;
    __shared__ float tl[64][65];
    const __bf16* vb = V + (((long)b * HH + h) * TT + t0) * HD;
    for (int i = tid; i < 64 * 64; i += 256)
        tl[i >> 6][i & 63] = (float)vb[i];
    __syncthreads();
    __bf16* ob = vT + ((long)b * HH + h) * HD * TT + t0;
    for (int i = tid; i < 64 * 64; i += 256) {
        const int d = i >> 6, t = i & 63;
        ob[(long)d * TT + t] = (__bf16)tl[t][d];
    }
}

// ---------------------------------------------------------------------------
// Extract the 16 random key columns per row (rows 32..2047).
// ---------------------------------------------------------------------------
__global__ __launch_bounds__(64) void extract_rand(
    const void* __restrict__ maskp, int* __restrict__ rand_idx)
{
    const int row = blockIdx.x + 32;
    const int lane = threadIdx.x;
    const unsigned char* m8 = (const unsigned char*)maskp;
    const int* m32 = (const int*)maskp;
    const bool u8 = (m8[1] != 0);

    int loc[16];
    int cnt = 0;
    const int c0 = lane * 32;
    for (int t = 0; t < 32; t++) {
        int c = c0 + t;
        int d = c - row;
        if (c >= 32 && (d > 64 || d < -64)) {
            int mv = u8 ? (int)m8[(long)row * TT + c] : m32[(long)row * TT + c];
            if (mv && cnt < 16) loc[cnt++] = c;
        }
    }
    int incl = cnt;
    for (int d = 1; d < 64; d <<= 1) {
        int n = __shfl_up(incl, d, 64);
        if (lane >= d) incl += n;
    }
    const int excl = incl - cnt;
    for (int i = 0; i < cnt; i++) {
        int p = excl + i;
        if (p < 16) rand_idx[(long)row * 16 + p] = loc[i];
    }
    const int total = __shfl(incl, 63, 64);
    if (lane == 0)
        for (int p = total; p < 16; p++) rand_idx[(long)row * 16 + p] = -1;
}

// ---------------------------------------------------------------------------
// Dense rows 0..31, MFMA flash partials; XCD-pinned 1D grid (192 blocks).
// ---------------------------------------------------------------------------
#define DPROWB 512
#define SW(r) (((r) & 7) << 4)

__global__ __launch_bounds__(256) void bb_dense2(
    const __bf16* __restrict__ Qb, const __bf16* __restrict__ Kb,
    const __bf16* __restrict__ vT, float* __restrict__ part)
{
    const int bid = blockIdx.x;
    const int xcd = bid & 7;
    const int idx = bid >> 3;           // 0..23
    const int gsel = idx >> 3;          // 0..2
    const int ch = idx & 7;
    const int grp = xcd + 8 * gsel;
    const int b = grp / HH, h = grp % HH;

    const int tid = threadIdx.x;
    const int w = tid >> 6, lane = tid & 63;
    const int fq = lane >> 4, fr = lane & 15;
    const int qh = w & 1, kr = w >> 1;
    const int k0 = ch * 256;

    __shared__ __attribute__((aligned(16))) char Pmem[32 * DPROWB];
    __shared__ float mbuf[2][32], lbuf[2][32];

    const __bf16* qbase = Qb + ((long)b * HH + h) * TT * HD;
    const __bf16* kbase = Kb + ((long)b * HH + h) * TT * HD;
    const __bf16* vTbase = vT + ((long)b * HH + h) * HD * TT;

    bf16x8 aq[2];
    #pragma unroll
    for (int kk = 0; kk < 2; kk++)
        aq[kk] = *(const bf16x8*)(qbase + (long)(qh * 16 + fr) * HD + kk * 32 + fq * 8);

    f32x4 sc[8];
    #pragma unroll
    for (int t = 0; t < 8; t++) {
        const int key = k0 + (kr * 8 + t) * 16 + fr;
        f32x4 c = {};
        #pragma unroll
        for (int kk = 0; kk < 2; kk++) {
            const bf16x8 bk = *(const bf16x8*)(kbase + (long)key * HD + kk * 32 + fq * 8);
            c = __builtin_amdgcn_mfma_f32_16x16x32_bf16(aq[kk], bk, c, 0, 0, 0);
        }
        sc[t] = c;
    }

    float rmax[4] = {-INFINITY, -INFINITY, -INFINITY, -INFINITY};
    #pragma unroll
    for (int t = 0; t < 8; t++)
        #pragma unroll
        for (int j = 0; j < 4; j++) {
            sc[t][j] *= 0.125f;
            rmax[j] = fmaxf(rmax[j], sc[t][j]);
        }
    #pragma unroll
    for (int o = 1; o < 16; o <<= 1)
        #pragma unroll
        for (int j = 0; j < 4; j++)
            rmax[j] = fmaxf(rmax[j], __shfl_xor(rmax[j], o, 64));
    if (fr == 0)
        #pragma unroll
        for (int j = 0; j < 4; j++)
            mbuf[kr][qh * 16 + fq * 4 + j] = rmax[j];

    __syncthreads();

    {
        float nm[4], lsum[4] = {};
        #pragma unroll
        for (int j = 0; j < 4; j++) {
            const int rl = qh * 16 + fq * 4 + j;
            nm[j] = fmaxf(mbuf[0][rl], mbuf[1][rl]);
        }
        #pragma unroll
        for (int t = 0; t < 8; t++)
            #pragma unroll
            for (int j = 0; j < 4; j++) {
                const float p = __expf(sc[t][j] - nm[j]);
                sc[t][j] = p;
                lsum[j] += p;
            }
        #pragma unroll
        for (int o = 1; o < 16; o <<= 1)
            #pragma unroll
            for (int j = 0; j < 4; j++)
                lsum[j] += __shfl_xor(lsum[j], o, 64);
        if (fr == 0)
            #pragma unroll
            for (int j = 0; j < 4; j++)
                lbuf[kr][qh * 16 + fq * 4 + j] = lsum[j];
        #pragma unroll
        for (int t = 0; t < 8; t++) {
            const int colc = (kr * 8 + t) * 16 + fr;
            #pragma unroll
            for (int j = 0; j < 4; j++) {
                const int rl = qh * 16 + fq * 4 + j;
                *(__bf16*)(Pmem + ((rl * DPROWB + colc * 2) ^ SW(rl))) = (__bf16)sc[t][j];
            }
        }
    }
    __syncthreads();

    f32x4 ov[2] = {};
    {
        const int rl = qh * 16 + fr;
        #pragma unroll
        for (int t = 0; t < 8; t++) {
            const bf16x8 ap = *(const bf16x8*)(Pmem + ((rl * DPROWB + (t * 32 + fq * 8) * 2) ^ SW(rl)));
            #pragma unroll
            for (int ti = 0; ti < 2; ti++) {
                const int d = kr * 32 + ti * 16 + fr;
                const bf16x8 bv = *(const bf16x8*)(vTbase + (long)d * TT + k0 + t * 32 + fq * 8);
                ov[ti] = __builtin_amdgcn_mfma_f32_16x16x32_bf16(ap, bv, ov[ti], 0, 0, 0);
            }
        }
    }
    __syncthreads();

    float* Ob = (float*)Pmem;
    #pragma unroll
    for (int ti = 0; ti < 2; ti++)
        #pragma unroll
        for (int j = 0; j < 4; j++)
            Ob[(qh * 16 + fq * 4 + j) * 68 + kr * 32 + ti * 16 + fr] = ov[ti][j];
    __syncthreads();

    {
        const int r = tid >> 3, g = tid & 7;
        float* pb = part + ((((long)b * HH + h) * 8 + ch) * 32 + r) * 66;
        if (g == 0) {
            pb[0] = fmaxf(mbuf[0][r], mbuf[1][r]);
            pb[1] = lbuf[0][r] + lbuf[1][r];
        }
        #pragma unroll
        for (int e = 0; e < 8; e++)
            pb[2 + g * 8 + e] = Ob[r * 68 + g * 8 + e];
    }
}

__global__ __launch_bounds__(256) void bb_dense_combine(
    const float* __restrict__ part, __bf16* __restrict__ Ao)
{
    const int h = blockIdx.x, b = blockIdx.y;
    const int tid = threadIdx.x;
    const int r = tid >> 3, dsl = (tid & 7) * 8;
    const float* pb = part + (((long)b * HH + h) * 8 * 32 + r) * 66;
    float M = -INFINITY;
    #pragma unroll
    for (int c = 0; c < 8; c++) M = fmaxf(M, pb[(long)c * 32 * 66]);
    float L = 0.f, o[8] = {};
    #pragma unroll
    for (int c = 0; c < 8; c++) {
        const float* pc = pb + (long)c * 32 * 66;
        const float w = __expf(pc[0] - M);
        L += w * pc[1];
        #pragma unroll
        for (int j = 0; j < 8; j++) o[j] += w * pc[2 + dsl + j];
    }
    const float inv = 1.f / L;
    const long ob = ((long)b * TT + r) * DD + h * HD + dsl;
    #pragma unroll
    for (int j = 0; j < 8; j++) Ao[ob + j] = (__bf16)(o[j] * inv);
}

// ---------------------------------------------------------------------------
// Sparse rows 32..2047; XCD-pinned 1D grid (1512 blocks), early rand-V
// prefetch, separate Obuf (3 barriers).
// ---------------------------------------------------------------------------
#define PROWB 384

__global__ __launch_bounds__(256) void bb_sparse2(
    const __bf16* __restrict__ Qb, const __bf16* __restrict__ Kb,
    const __bf16* __restrict__ Vb, const __bf16* __restrict__ vT,
    const int* __restrict__ rand_idx, __bf16* __restrict__ Ao)
{
    const int bid = blockIdx.x;
    const int xcd = bid & 7;
    const int idx = bid >> 3;            // 0..188
    const int gsel = idx / 63;           // 0..2
    const int tq  = idx % 63;
    const int grp = xcd + 8 * gsel;      // b*HH+h
    const int b = grp / HH, h = grp % HH;
    const int q0 = (tq + 1) * 32;

    const int tid = threadIdx.x;
    const int w = tid >> 6, lane = tid & 63;
    const int fq = lane >> 4, fr = lane & 15;
    const int qh = w & 1, kr = w >> 1;

    const int lo = max(32, q0 - 64);
    const int hi = min(TT - 1, q0 + 95);

    __shared__ __attribute__((aligned(16))) char Pmem[32 * PROWB];
    __shared__ float Obuf[32][68];
    __shared__ float mbuf[2][32], lbuf[2][32], mrand[32], lrand[32];

    const __bf16* qbase = Qb + ((long)b * HH + h) * TT * HD;
    const __bf16* kbase = Kb + ((long)b * HH + h) * TT * HD;
    const __bf16* vbase = Vb + ((long)b * HH + h) * TT * HD;
    const __bf16* vTbase = vT + ((long)b * HH + h) * HD * TT;

    // ---- rand indices first (longest dependency chain) ----
    const int rr_r = tid >> 3;
    const int g = tid & 7;
    const int grow_r = q0 + rr_r;
    int crand[16];
    {
        const int4* rrv = (const int4*)(rand_idx + (long)grow_r * 16);
        #pragma unroll
        for (int c4 = 0; c4 < 4; c4++) {
            const int4 rv = rrv[c4];
            crand[c4 * 4 + 0] = rv.x; crand[c4 * 4 + 1] = rv.y;
            crand[c4 * 4 + 2] = rv.z; crand[c4 * 4 + 3] = rv.w;
        }
    }

    // ---- S = Q K^T (MFMA, global fragments) ----
    bf16x8 aq[2];
    #pragma unroll
    for (int kk = 0; kk < 2; kk++)
        aq[kk] = *(const bf16x8*)(qbase + (long)(q0 + qh * 16 + fr) * HD + kk * 32 + fq * 8);

    f32x4 sc[6];
    #pragma unroll
    for (int t6 = 0; t6 < 6; t6++) {
        const int colg = (kr * 6 + t6) * 16 + fr;
        const int keyg = colg < 32 ? colg : lo + colg - 32;
        const int keyc = min(keyg, TT - 1);
        f32x4 c = {};
        #pragma unroll
        for (int kk = 0; kk < 2; kk++) {
            const bf16x8 bk = *(const bf16x8*)(kbase + (long)keyc * HD + kk * 32 + fq * 8);
            c = __builtin_amdgcn_mfma_f32_16x16x32_bf16(aq[kk], bk, c, 0, 0, 0);
        }
        sc[t6] = c;
    }

    float rmax[4] = {-INFINITY, -INFINITY, -INFINITY, -INFINITY};
    #pragma unroll
    for (int t6 = 0; t6 < 6; t6++) {
        const int colg = (kr * 6 + t6) * 16 + fr;
        const int keyg = colg < 32 ? colg : lo + colg - 32;
        #pragma unroll
        for (int j = 0; j < 4; j++) {
            const int grow = q0 + qh * 16 + fq * 4 + j;
            const int dlt = keyg - grow;
            const bool valid = (colg < 32) || (keyg <= hi && dlt <= 64 && dlt >= -64);
            const float v = valid ? sc[t6][j] * 0.125f : -INFINITY;
            sc[t6][j] = v;
            rmax[j] = fmaxf(rmax[j], v);
        }
    }
    #pragma unroll
    for (int o = 1; o < 16; o <<= 1)
        #pragma unroll
        for (int j = 0; j < 4; j++)
            rmax[j] = fmaxf(rmax[j], __shfl_xor(rmax[j], o, 64));
    if (fr == 0)
        #pragma unroll
        for (int j = 0; j < 4; j++)
            mbuf[kr][qh * 16 + fq * 4 + j] = rmax[j];

    // ---- rand scores + early V prefetch (first 8 rows) ----
    const bf16x8 q8 = *(const bf16x8*)(qbase + (long)grow_r * HD + g * 8);
    float srand[16];
    bf16x8 vf0[8];
    #pragma unroll
    for (int j = 0; j < 8; j++)
        vf0[j] = *(const bf16x8*)(vbase + (long)max(crand[j], 0) * HD + g * 8);
    #pragma unroll
    for (int ch = 0; ch < 2; ch++) {
        bf16x8 kf[8];
        #pragma unroll
        for (int j = 0; j < 8; j++)
            kf[j] = *(const bf16x8*)(kbase + (long)max(crand[ch * 8 + j], 0) * HD + g * 8);
        #pragma unroll
        for (int j = 0; j < 8; j++) {
            float s = 0.f;
            #pragma unroll
            for (int e = 0; e < 8; e++) s += (float)q8[e] * (float)kf[j][e];
            s += __shfl_xor(s, 1, 64);
            s += __shfl_xor(s, 2, 64);
            s += __shfl_xor(s, 4, 64);
            srand[ch * 8 + j] = crand[ch * 8 + j] >= 0 ? s * 0.125f : -INFINITY;
        }
    }
    float mr = -INFINITY;
    #pragma unroll
    for (int j = 0; j < 16; j++) mr = fmaxf(mr, srand[j]);
    if (g == 0) mrand[rr_r] = mr;

    __syncthreads();   // barrier 1

    {
        float nm[4], lsum[4] = {};
        #pragma unroll
        for (int j = 0; j < 4; j++) {
            const int rl = qh * 16 + fq * 4 + j;
            nm[j] = fmaxf(fmaxf(mbuf[0][rl], mbuf[1][rl]), mrand[rl]);
        }
        #pragma unroll
        for (int t6 = 0; t6 < 6; t6++)
            #pragma unroll
            for (int j = 0; j < 4; j++) {
                const float p = __expf(sc[t6][j] - nm[j]);
                sc[t6][j] = p;
                lsum[j] += p;
            }
        #pragma unroll
        for (int o = 1; o < 16; o <<= 1)
            #pragma unroll
            for (int j = 0; j < 4; j++)
                lsum[j] += __shfl_xor(lsum[j], o, 64);
        if (fr == 0)
            #pragma unroll
            for (int j = 0; j < 4; j++)
                lbuf[kr][qh * 16 + fq * 4 + j] = lsum[j];
        #pragma unroll
        for (int t6 = 0; t6 < 6; t6++) {
            const int key = (kr * 6 + t6) * 16 + fr;
            #pragma unroll
            for (int j = 0; j < 4; j++) {
                const int rl = qh * 16 + fq * 4 + j;
                *(__bf16*)(Pmem + ((rl * PROWB + key * 2) ^ SW(rl))) = (__bf16)sc[t6][j];
            }
        }
    }

    float prand[16];
    {
        const float nmr = fmaxf(fmaxf(mbuf[0][rr_r], mbuf[1][rr_r]), mrand[rr_r]);
        float lr = 0.f;
        #pragma unroll
        for (int j = 0; j < 16; j++) {
            prand[j] = __expf(srand[j] - nmr);
            lr += prand[j];
        }
        if (g == 0) lrand[rr_r] = lr;
    }

    __syncthreads();   // barrier 2

    // ---- rand PV: second-half V loads issued first, then multiply ----
    float arand[8] = {};
    {
        bf16x8 vf1[8];
        #pragma unroll
        for (int j = 0; j < 8; j++)
            vf1[j] = *(const bf16x8*)(vbase + (long)max(crand[8 + j], 0) * HD + g * 8);
        #pragma unroll
        for (int j = 0; j < 8; j++) {
            const float p = prand[j];
            #pragma unroll
            for (int e = 0; e < 8; e++) arand[e] += p * (float)vf0[j][e];
        }
        #pragma unroll
        for (int j = 0; j < 8; j++) {
            const float p = prand[8 + j];
            #pragma unroll
            for (int e = 0; e < 8; e++) arand[e] += p * (float)vf1[j][e];
        }
    }

    // ---- O = P V : MFMA, P from LDS, V^T fragments from global ----
    f32x4 ov[2] = {};
    {
        const int rl = qh * 16 + fr;
        #pragma unroll
        for (int t = 0; t < 6; t++) {
            const bf16x8 ap = *(const bf16x8*)(Pmem + ((rl * PROWB + (t * 32 + fq * 8) * 2) ^ SW(rl)));
            const int key0 = t * 32 + fq * 8;
            int tg = key0 < 32 ? key0 : lo + key0 - 32;
            tg = min(tg, TT - 8);
            #pragma unroll
            for (int ti = 0; ti < 2; ti++) {
                const int d = kr * 32 + ti * 16 + fr;
                const bf16x8 bv = *(const bf16x8*)(vTbase + (long)d * TT + tg);
                ov[ti] = __builtin_amdgcn_mfma_f32_16x16x32_bf16(ap, bv, ov[ti], 0, 0, 0);
            }
        }
    }

    #pragma unroll
    for (int ti = 0; ti < 2; ti++)
        #pragma unroll
        for (int j = 0; j < 4; j++)
            Obuf[qh * 16 + fq * 4 + j][kr * 32 + ti * 16 + fr] = ov[ti][j];

    __syncthreads();   // barrier 3: Obuf visible

    {
        const float linv = 1.f /
            (lbuf[0][rr_r] + lbuf[1][rr_r] + lrand[rr_r]);
        bf16x8 o8;
        #pragma unroll
        for (int e = 0; e < 8; e++)
            o8[e] = (__bf16)((Obuf[rr_r][g * 8 + e] + arand[e]) * linv);
        *(bf16x8*)(Ao + ((long)b * TT + grow_r) * DD + h * HD + g * 8) = o8;
    }
}

// ---------------------------------------------------------------------------
extern "C" void kernel_launch(void* const* d_in, const int* in_sizes, int n_in,
                              void* d_out, int out_size, void* d_ws, size_t ws_size,
                              hipStream_t stream)
{
    const float* x  = (const float*)d_in[0];
    const float* Wq = (const float*)d_in[1];
    const float* bq = (const float*)d_in[2];
    const float* Wk = (const float*)d_in[3];
    const float* bk = (const float*)d_in[4];
    const float* Wv = (const float*)d_in[5];
    const float* bv = (const float*)d_in[6];
    const float* Wo = (const float*)d_in[7];
    const float* bo = (const float*)d_in[8];
    const void*  mask = d_in[9];

    __bf16* xb   = (__bf16*)d_ws;
    __bf16* qkvb = xb + BTD;
    __bf16* vTb  = qkvb + 3 * BTD;
    __bf16* aob  = vTb + BTD;
    __bf16* Wcat = aob + BTD;
    __bf16* Wob  = Wcat + (long)3 * DD * DD;
    int*    rand_idx = (int*)(Wob + (long)DD * DD);
    float*  part = (float*)(rand_idx + (long)TT * 16);

    extract_rand<<<TT - 32, 64, 0, stream>>>(mask, rand_idx);

    const int WN4 = DD * DD / 4;
    cvt_bf16<<<(int)(BTD / 4 + 255) / 256, 256, 0, stream>>>(x, xb, (int)(BTD / 4));
    cvt_w4<<<dim3((WN4 + 255) / 256, 4), 256, 0, stream>>>(Wq, Wk, Wv, Wo, Wcat, Wob);

    mfma_gemm<<<dim3(3 * DD / 128, MM / 128), 256, 0, stream>>>(
        xb, Wcat, bq, bk, bv, nullptr, qkvb, 3 * DD, 1);

    vt_transpose<<<768, 256, 0, stream>>>(qkvb + 2 * BTD, vTb);

    bb_dense2<<<192, 256, 0, stream>>>(qkvb, qkvb + BTD, vTb, part);
    bb_dense_combine<<<dim3(HH, BB), 256, 0, stream>>>(part, aob);

    bb_sparse2<<<1512, 256, 0, stream>>>(
        qkvb, qkvb + BTD, qkvb + 2 * BTD, vTb, rand_idx, aob);

    mfma_gemm<<<dim3(DD / 128, MM / 128), 256, 0, stream>>>(
        aob, Wob, bo, bo, bo, (float*)d_out, nullptr, DD, 0);
}